// Round 5
// baseline (758.038 us; speedup 1.0000x reference)
//
#include <hip/hip_runtime.h>

#define DEV __device__ __forceinline__

typedef short bf16x8 __attribute__((ext_vector_type(8)));
typedef float f32x4 __attribute__((ext_vector_type(4)));

static const int NVOX = 262144; // 64^3

DEV float bflo(unsigned int u) { return __uint_as_float(u << 16); }
DEV float bfhi(unsigned int u) { return __uint_as_float(u & 0xffff0000u); }
DEV float bf2f(unsigned short s) { return __uint_as_float(((unsigned int)s) << 16); }
DEV unsigned short f2bf(float f) {
    unsigned int x = __float_as_uint(f);
    x += 0x7fffu + ((x >> 16) & 1u);   // RNE
    return (unsigned short)(x >> 16);
}
// dual-dtype raw-input load: f==1 -> fp32, f==0 -> bf16
DEV float ldin(const void* p, int i, int f) {
    return f ? ((const float*)p)[i] : bf2f(((const unsigned short*)p)[i]);
}

// async 16B global->LDS DMA. LDS dest = wave-uniform base + lane*16.
DEV void gld16(const unsigned short* g, unsigned short* l) {
    __builtin_amdgcn_global_load_lds(
        (const __attribute__((address_space(1))) unsigned int*)g,
        (__attribute__((address_space(3))) unsigned int*)l, 16, 0, 0);
}

// ---------------------------------------------------------------------------
// Dtype sniffer (insurance; fp32 inputs confirmed).
// ---------------------------------------------------------------------------
__global__ void sniff_kernel(const unsigned short* __restrict__ src, int* __restrict__ flag) {
    __shared__ int cnt[256];
    int t = threadIdx.x;
    int c = 0;
    for (int i = t; i < 4096; i += 256) {
        unsigned int u = (unsigned int)src[i] & 0x7fffu;
        c += (u >= 0x4900u) ? 1 : 0;
    }
    cnt[t] = c;
    __syncthreads();
    for (int s = 128; s > 0; s >>= 1) {
        if (t < s) cnt[t] += cnt[t + s];
        __syncthreads();
    }
    if (t == 0) *flag = (cnt[0] > 8) ? 1 : 0;
}

// ---------------------------------------------------------------------------
// Weight prep into MFMA B-fragment order (unchanged from R4).
// ---------------------------------------------------------------------------
__global__ void prep_kernel(const void* __restrict__ w1, const void* __restrict__ w2,
                            const void* __restrict__ bsv, const void* __restrict__ btv,
                            const void* __restrict__ b1v, const void* __restrict__ b2v,
                            const int* __restrict__ flag,
                            unsigned short* __restrict__ Wf1,
                            unsigned short* __restrict__ Wf2,
                            float* __restrict__ fbias) {
    const int f = *flag;
    int idx = blockIdx.x * 256 + threadIdx.x;
    const int N1  = 27 * 4 * 4 * 512;   // 221184 (main, kc<4)
    const int N1E = 2 * 4 * 512;        //   4096 (tail)
    const int N2  = 27 * 2 * 4 * 512;   // 110592
    if (idx < N1) {
        int frag = idx >> 9;           // (tap*4 + kc)*4 + nt
        int r    = idx & 511;
        int lane = r >> 3, j = r & 7;
        int nt = frag & 3;
        int tk = frag >> 2;            // tap*4 + kc
        int tap = tk >> 2, kc = tk & 3;
        int o  = nt * 16 + (lane & 15);
        int cp = kc * 32 + (lane >> 4) * 8 + j;   // < 128 always
        Wf1[idx] = f2bf(ldin(w1, (o * 130 + cp) * 27 + tap, f));
    } else if (idx < N1 + N1E) {
        int i2 = idx - N1;
        int frag = i2 >> 9;            // kc*4 + nt (kc<2)
        int r    = i2 & 511;
        int lane = r >> 3, j = r & 7;
        int nt = frag & 3, kc = frag >> 2;
        int o   = nt * 16 + (lane & 15);
        int kap = kc * 32 + (lane >> 4) * 8 + j;  // kappa = tap*2 + ch
        unsigned short val = 0;
        if (kap < 54) {
            int tap = kap >> 1, ch = 128 + (kap & 1);
            val = f2bf(ldin(w1, (o * 130 + ch) * 27 + tap, f));
        }
        Wf1[idx] = val;                // Wf1e contiguous after Wf1
    } else if (idx < N1 + N1E + N2) {
        int i2 = idx - N1 - N1E;
        int frag = i2 >> 9;            // (tap*2 + kc)*4 + nt
        int r    = i2 & 511;
        int lane = r >> 3, j = r & 7;
        int nt = frag & 3;
        int tk = frag >> 2;
        int tap = tk >> 1, kc = tk & 1;
        int o = nt * 16 + (lane & 15);
        int c = kc * 32 + (lane >> 4) * 8 + j;
        Wf2[i2] = f2bf(ldin(w2, (o * 64 + c) * 27 + tap, f));
    } else if (idx < N1 + N1E + N2 + 256) {
        int j = idx - N1 - N1E - N2;
        const void* bp = (j < 64) ? bsv : (j < 128) ? btv : (j < 192) ? b1v : b2v;
        fbias[j] = ldin(bp, j & 63, f);
    }
}

// ---------------------------------------------------------------------------
// Projection (1x1x1 conv 32->64) + L2 normalize over channels.
// ---------------------------------------------------------------------------
__global__ __launch_bounds__(256) void proj_kernel(
        const void* __restrict__ Xsrc, const void* __restrict__ Xtgt,
        const void* __restrict__ Wsrc, const void* __restrict__ Wtgt,
        const float* __restrict__ fbias, const int* __restrict__ flag,
        unsigned short* __restrict__ SP, unsigned short* __restrict__ TP) {
    const int f = *flag;
    const void* Xin = blockIdx.y ? Xtgt : Xsrc;
    const void* W   = blockIdx.y ? Wtgt : Wsrc;
    const float* Bb = fbias + (blockIdx.y ? 64 : 0);
    unsigned short* Outp = blockIdx.y ? TP : SP;

    __shared__ float ws[2048];   // [ci][o]
    const int t = threadIdx.x;
    for (int i = t; i < 2048; i += 256) {
        int ci = i >> 6, o = i & 63;
        ws[i] = ldin(W, o * 32 + ci, f);
    }
    __syncthreads();

    const size_t v = (size_t)blockIdx.x * 256 + t;
    float acc[64];
#pragma unroll
    for (int o = 0; o < 64; ++o) acc[o] = Bb[o];
    if (f) {
        const float* Xf = (const float*)Xin;
        for (int ci = 0; ci < 32; ++ci) {
            float x = Xf[(size_t)ci * NVOX + v];
            const float4* wr = (const float4*)(ws + ci * 64);
#pragma unroll
            for (int o4 = 0; o4 < 16; ++o4) {
                float4 w4 = wr[o4];
                acc[o4 * 4 + 0] = fmaf(w4.x, x, acc[o4 * 4 + 0]);
                acc[o4 * 4 + 1] = fmaf(w4.y, x, acc[o4 * 4 + 1]);
                acc[o4 * 4 + 2] = fmaf(w4.z, x, acc[o4 * 4 + 2]);
                acc[o4 * 4 + 3] = fmaf(w4.w, x, acc[o4 * 4 + 3]);
            }
        }
    } else {
        const unsigned short* Xb = (const unsigned short*)Xin;
        for (int ci = 0; ci < 32; ++ci) {
            float x = bf2f(Xb[(size_t)ci * NVOX + v]);
            const float4* wr = (const float4*)(ws + ci * 64);
#pragma unroll
            for (int o4 = 0; o4 < 16; ++o4) {
                float4 w4 = wr[o4];
                acc[o4 * 4 + 0] = fmaf(w4.x, x, acc[o4 * 4 + 0]);
                acc[o4 * 4 + 1] = fmaf(w4.y, x, acc[o4 * 4 + 1]);
                acc[o4 * 4 + 2] = fmaf(w4.z, x, acc[o4 * 4 + 2]);
                acc[o4 * 4 + 3] = fmaf(w4.w, x, acc[o4 * 4 + 3]);
            }
        }
    }
    float s = 0.f;
#pragma unroll
    for (int o = 0; o < 64; ++o) s = fmaf(acc[o], acc[o], s);
    float scale = 1.f / fmaxf(sqrtf(s), 1e-12f);

    unsigned int pk[32];
#pragma unroll
    for (int o = 0; o < 32; ++o)
        pk[o] = (unsigned int)f2bf(acc[2 * o] * scale) |
                ((unsigned int)f2bf(acc[2 * o + 1] * scale) << 16);
    uint4* outp = (uint4*)(Outp + v * 64);
#pragma unroll
    for (int j = 0; j < 8; ++j)
        outp[j] = make_uint4(pk[4 * j], pk[4 * j + 1], pk[4 * j + 2], pk[4 * j + 3]);
}

// ---------------------------------------------------------------------------
// Correlation via MFMA (banded implicit GEMM).
//  - A fragments loop-invariant -> loaded ONCE from global (spb eliminated)
//  - TP staging via global_load_lds with pre-swizzled source (linear LDS dest,
//    XOR-swizzled read) -- rule #21 both-sides swizzle
//  - LDS 36.9 KB -> 4 blocks/CU
// ---------------------------------------------------------------------------
__global__ __launch_bounds__(256) void corr_kernel(
        const unsigned short* __restrict__ SP, const unsigned short* __restrict__ TP,
        unsigned short* __restrict__ X1, float* __restrict__ Out) {
    __shared__ __align__(16) unsigned short tpb[2][80 * 64];   // 20480 B
    __shared__ __align__(16) unsigned short stage[64 * 128];   // 16384 B

    const int t = threadIdx.x;
    const int wv = t >> 6, lane = t & 63;
    const int q = lane >> 4, l16 = lane & 15;
    const int x0 = wv * 16;

    // XCD-aware bijective swizzle: XCD k gets z-slices [8k, 8k+8)
    const int bid = blockIdx.x;
    const int wg = (bid & 7) * 512 + (bid >> 3);
    const int z = wg >> 6, y = wg & 63;
    const size_t vbase = ((size_t)z * 64 + y) * 64;

    // A fragments once from global (loop-invariant across all 25 iterations)
    const unsigned short* arow = SP + (vbase + x0 + l16) * 64 + q * 8;
    const bf16x8 a0 = *(const bf16x8*)(arow);
    const bf16x8 a1 = *(const bf16x8*)(arow + 32);

    // DMA staging: 640 chunks (80 pos x 8). Loads 0,1: all threads; load 2:
    // waves 0,1 only (wave-uniform branch -> full exec, no partial masking).
    auto stage_tp = [&](int it, int b) {
        const int zc = min(max(z + it / 5 - 2, 0), 63);
        const int yc = min(max(y + it % 5 - 2, 0), 63);
        const unsigned short* tb = TP + ((size_t)zc * 64 + yc) * 4096;
#pragma unroll
        for (int j = 0; j < 2; ++j) {
            int c = t + j * 256;
            int pp = c >> 3, cc = c & 7;
            int xc = min(max(pp - 2, 0), 63);
            gld16(tb + xc * 64 + ((cc ^ (pp & 7)) * 8),
                  &tpb[b][(wv * 64 + j * 256) * 8]);
        }
        if (wv < 2) {
            int c = 512 + wv * 64 + lane;
            int pp = c >> 3, cc = c & 7;
            int xc = min(max(pp - 2, 0), 63);
            gld16(tb + xc * 64 + ((cc ^ (pp & 7)) * 8),
                  &tpb[b][(512 + wv * 64) * 8]);
        }
    };

    stage_tp(0, 0);
    __syncthreads();

    int p = 0;
    for (int it = 0; it < 25; ++it) {
        if (it < 24) stage_tp(it + 1, p ^ 1);   // DMA overlaps compute below

        f32x4 acc[2] = {{0.f, 0.f, 0.f, 0.f}, {0.f, 0.f, 0.f, 0.f}};
        {
            const char* tb = (const char*)tpb[p];
#pragma unroll
            for (int nt = 0; nt < 2; ++nt) {
                const int pr = x0 + nt * 16 + l16;
                bf16x8 b0 = *(const bf16x8*)(tb + pr * 128 + ((q ^ (pr & 7)) * 16));
                bf16x8 b1 = *(const bf16x8*)(tb + pr * 128 + (((4 + q) ^ (pr & 7)) * 16));
                acc[nt] = __builtin_amdgcn_mfma_f32_16x16x32_bf16(a0, b0, acc[nt], 0, 0, 0);
                acc[nt] = __builtin_amdgcn_mfma_f32_16x16x32_bf16(a1, b1, acc[nt], 0, 0, 0);
            }
        }
        // band extraction: C row (m) = q*4+r, col (n) = l16; dxp = nt*16+l16-(q*4+r)
        const int kb = it * 5;
        char* sg = (char*)stage;
#pragma unroll
        for (int nt = 0; nt < 2; ++nt) {
#pragma unroll
            for (int r = 0; r < 4; ++r) {
                int ml = q * 4 + r;
                int dxp = nt * 16 + l16 - ml;     // dx + 2
                if ((unsigned)dxp < 5u) {
                    int xl = x0 + ml;
                    *(unsigned short*)(sg + xl * 256 + (((kb + dxp) * 2) ^ ((xl & 7) << 4))) =
                        f2bf(acc[nt][r]);
                }
            }
        }
        __syncthreads();
        p ^= 1;
    }

    // ---- deferred softmax tail: 4 lanes per voxel, all 256 threads ----
    {
        const int vox = t >> 2, part = t & 3;
        const int sx = (vox & 7) << 4;
        const char* sg = (const char*)stage;
        uint4 u[4];
#pragma unroll
        for (int j = 0; j < 4; ++j)
            u[j] = *(const uint4*)(sg + vox * 256 + ((part * 64 + j * 16) ^ sx));

        // pass 1: branchless top-2 over this lane's 32 values
        float m = -1e30f, s2 = -1e30f;
#pragma unroll
        for (int j = 0; j < 4; ++j) {
            const unsigned int uu[4] = {u[j].x, u[j].y, u[j].z, u[j].w};
#pragma unroll
            for (int w = 0; w < 4; ++w) {
                int k = part * 32 + j * 8 + w * 2;
                float d0 = (k < 125) ? bflo(uu[w]) : -1e30f;
                float d1 = (k + 1 < 125) ? bfhi(uu[w]) : -1e30f;
                float lo0 = fminf(d0, m); m = fmaxf(d0, m); s2 = fmaxf(s2, lo0);
                float lo1 = fminf(d1, m); m = fmaxf(d1, m); s2 = fmaxf(s2, lo1);
            }
        }
        // merge top-2 across the voxel's 4 lanes
#pragma unroll
        for (int off = 1; off <= 2; off <<= 1) {
            float om = __shfl_xor(m, off, 64);
            float os = __shfl_xor(s2, off, 64);
            float lo = fminf(m, om);
            m = fmaxf(m, om);
            s2 = fmaxf(fmaxf(s2, os), lo);
        }
        // pass 2: exp sums with incremental (dx,dy,dz)
        int kk = part * 32;
        int dz0 = kk / 25, rem = kk - dz0 * 25, dy0 = rem / 5, dx0 = rem - dy0 * 5;
        float fx = (float)(dx0 - 2), fy = (float)(dy0 - 2), fz = (float)(dz0 - 2);
        float Zs = 0.f, S1 = 0.f, Ox = 0.f, Oy = 0.f, Oz = 0.f;
#pragma unroll
        for (int j = 0; j < 4; ++j) {
            const unsigned int uu[4] = {u[j].x, u[j].y, u[j].z, u[j].w};
#pragma unroll
            for (int w = 0; w < 8; ++w) {
                int k = part * 32 + j * 8 + w;
                bool ok = (k < 125);
                float d = (w & 1) ? bfhi(uu[w >> 1]) : bflo(uu[w >> 1]);
                d = ok ? d : 0.f;                 // sanitize: garbage slot may be NaN
                float e = ok ? __expf(d - m) : 0.f;
                Zs += e; S1 = fmaf(e, d, S1);
                Ox = fmaf(e, fx, Ox); Oy = fmaf(e, fy, Oy); Oz = fmaf(e, fz, Oz);
                fx += 1.f;
                if (fx > 2.5f) { fx = -2.f; fy += 1.f; if (fy > 2.5f) { fy = -2.f; fz += 1.f; } }
            }
        }
        // quad reduce the 5 sums
#pragma unroll
        for (int off = 1; off <= 2; off <<= 1) {
            Zs += __shfl_xor(Zs, off, 64);
            S1 += __shfl_xor(S1, off, 64);
            Ox += __shfl_xor(Ox, off, 64);
            Oy += __shfl_xor(Oy, off, 64);
            Oz += __shfl_xor(Oz, off, 64);
        }
        if (part == 0) {
            float inv  = 1.f / fmaxf(Zs, 1e-8f);
            float eoz = Oz * inv, eoy = Oy * inv, eox = Ox * inv;
            float conf = fminf(inv, 1.f);
            float marg = fmaxf(conf - __expf(s2 - m) * inv, 0.f);
            float ent  = m + __logf(fmaxf(Zs, 1e-8f)) - S1 * inv;
            char* sgw = (char*)stage;
            *(unsigned short*)(sgw + vox * 256 + (250 ^ sx)) = f2bf(eoz);
            *(unsigned short*)(sgw + vox * 256 + (252 ^ sx)) = f2bf(eoy);
            *(unsigned short*)(sgw + vox * 256 + (254 ^ sx)) = f2bf(eox);
            const size_t v = vbase + vox;
            *(unsigned int*)(X1 + v * 160 + 128) =
                (unsigned int)f2bf(conf) | ((unsigned int)f2bf(ent) << 16);
            Out[v]                    = eoz;
            Out[(size_t)NVOX + v]     = eoy;
            Out[(size_t)2 * NVOX + v] = eox;
            Out[(size_t)3 * NVOX + v] = conf;
            Out[(size_t)4 * NVOX + v] = marg;
            Out[(size_t)5 * NVOX + v] = ent;
        }
    }
    __syncthreads();

    // X1 flush: ch 0..127 (corr + offsets), 64 vox x 16 uint4
#pragma unroll
    for (int j = 0; j < 4; ++j) {
        int i = t + j * 256;
        int vox = i >> 4, cc = i & 15;
        *(uint4*)(X1 + (vbase + vox) * 160 + (size_t)cc * 8) =
            *(const uint4*)((const char*)stage + vox * 256 + ((cc * 16) ^ ((vox & 7) << 4)));
    }
}

// ---------------------------------------------------------------------------
// 3x3x3 conv, implicit GEMM via mfma_f32_16x16x32_bf16, zero padding.
// v2: global_load_lds staging (pre-swizzled source, linear LDS dest, XOR-
// swizzled reads), halo rows 0/65 pre-zeroed once (always out-of-volume),
// invalid (zz,yy) rows skip both stage and MFMA (zero-pad semantics).
// conv1: 33.8 KB LDS, 4 blocks/CU. conv2: 16.9 KB, __launch_bounds__ 6/CU.
// ---------------------------------------------------------------------------
template <int XSTRIDE, int CPAD, int KC, int NLD, int MINW, bool TAIL>
__global__ __launch_bounds__(256, MINW) void conv3_kernel(
        const unsigned short* __restrict__ Xin, const unsigned short* __restrict__ Wf,
        const unsigned short* __restrict__ Wfe,
        const float* __restrict__ Bias, unsigned short* __restrict__ Out) {
    __shared__ __align__(16) unsigned short rowbuf[2][66 * CPAD];
    const int lin = blockIdx.x;
    const int z = (lin & 7) * 8 + ((lin >> 3) >> 6);
    const int y = (lin >> 3) & 63;
    const int t = threadIdx.x;
    const int wv = t >> 6, lane = t & 63;
    const int quad = lane >> 4, l16 = lane & 15;
    const int mt2 = (wv & 1) * 2;    // m-tile pair base
    const int nt2 = (wv >> 1) * 2;   // n-tile pair base
    const int CH16 = CPAD / 8;       // 16B chunks per row

    f32x4 acc[2][2] = {{{0.f,0.f,0.f,0.f},{0.f,0.f,0.f,0.f}},
                       {{0.f,0.f,0.f,0.f},{0.f,0.f,0.f,0.f}}};

    // DMA-stage rows 1..64 (x = 0..63) of plane (zz,yy) into rowbuf[b].
    // LDS slot (xi, cc') holds global chunk cc'^(xi&7) -> reads use same XOR.
    auto stage_row = [&](int zz, int yy, int b) {
        const unsigned short* base = Xin + (((size_t)zz * 64 + yy) * 64) * XSTRIDE;
#pragma unroll
        for (int i = 0; i < NLD; ++i) {
            int chunk = wv * 64 + lane + i * 256;        // 0 .. 64*CH16-1
            int xi = chunk / CH16 + 1;                   // LDS row 1..64
            int cc = chunk % CH16;
            gld16(base + (xi - 1) * XSTRIDE + ((cc ^ (xi & 7)) * 8),
                  &rowbuf[b][CPAD + (size_t)(wv * 64 + i * 256) * 8]);
        }
    };

    // prologue: stage iteration 0 (dz=-1,dy=-1) if valid
    {
        const int zz = z - 1, yy = y - 1;
        if ((unsigned)zz < 64u && (unsigned)yy < 64u) stage_row(zz, yy, 0);
    }

    if (TAIL) {
        // im2col gather of ch 128/129 neighborhoods into rowbuf[1] scratch:
        // ebuf[vox][kappa], kappa = tap*2 + ch, row stride 72 shorts.
        unsigned short* ebuf = &rowbuf[1][0];
#pragma unroll
        for (int i2 = 0; i2 < 8; ++i2) {
            int i = t + i2 * 256;                 // 0..2047
            int vox = i >> 5, slot = i & 31;
            unsigned int val = 0u;
            int kap;
            if (slot < 27) {
                int dz = slot / 9 - 1, dy = (slot / 3) % 3 - 1, dxx = slot % 3 - 1;
                int zz = z + dz, yy = y + dy, xx = vox + dxx;
                kap = slot * 2;
                if ((unsigned)zz < 64u && (unsigned)yy < 64u && (unsigned)xx < 64u)
                    val = *(const unsigned int*)(Xin + (((size_t)zz * 64 + yy) * 64 + xx) * XSTRIDE + 128);
            } else {
                kap = 54 + (slot - 27) * 2;       // zero-fill kappa 54..63
            }
            *(unsigned int*)(ebuf + vox * 72 + kap) = val;
        }
        __syncthreads();
#pragma unroll
        for (int kc = 0; kc < 2; ++kc) {
            bf16x8 bte[2];
#pragma unroll
            for (int nl = 0; nl < 2; ++nl)
                bte[nl] = *(const bf16x8*)(Wfe + (size_t)(kc * 4 + nt2 + nl) * 512 + lane * 8);
#pragma unroll
            for (int ml = 0; ml < 2; ++ml) {
                bf16x8 a = *(const bf16x8*)(ebuf + ((mt2 + ml) * 16 + l16) * 72 + (kc * 4 + quad) * 8);
#pragma unroll
                for (int nl = 0; nl < 2; ++nl)
                    acc[ml][nl] = __builtin_amdgcn_mfma_f32_16x16x32_bf16(a, bte[nl], acc[ml][nl], 0, 0, 0);
            }
        }
        __syncthreads();   // ebuf reads drained before halo-zero overwrites
    }

    // zero halo rows 0 and 65 of both buffers (x = -1 / 64: always outside)
    if (t < 4 * CH16) {
        int b = t / (2 * CH16), r2 = (t / CH16) & 1, c = t % CH16;
        *(uint4*)(&rowbuf[b][(size_t)(r2 * 65) * CPAD + c * 8]) = make_uint4(0u, 0u, 0u, 0u);
    }
    __syncthreads();   // drains prologue DMA + halo zeros

    int p = 0;
    for (int it = 0; it < 9; ++it) {
        // issue next plane's DMA (overlaps MFMA below)
        if (it < 8) {
            const int z2 = z + (it + 1) / 3 - 1, y2 = y + (it + 1) % 3 - 1;
            if ((unsigned)z2 < 64u && (unsigned)y2 < 64u) stage_row(z2, y2, p ^ 1);
        }
        const int zz = z + it / 3 - 1, yy = y + it % 3 - 1;
        if ((unsigned)zz < 64u && (unsigned)yy < 64u) {
            const unsigned short* rp = rowbuf[p];
#pragma unroll
            for (int dx = 0; dx < 3; ++dx) {
                const int tap = it * 3 + dx;
                const unsigned short* wt = Wf + ((size_t)tap * KC * 4) * 512 + lane * 8;
                bf16x8 bf[KC][2];
#pragma unroll
                for (int kc = 0; kc < KC; ++kc)
#pragma unroll
                    for (int nl = 0; nl < 2; ++nl)
                        bf[kc][nl] = *(const bf16x8*)(wt + (size_t)(kc * 4 + nt2 + nl) * 512);
#pragma unroll
                for (int kc = 0; kc < KC; ++kc) {
#pragma unroll
                    for (int ml = 0; ml < 2; ++ml) {
                        const int row = (mt2 + ml) * 16 + l16 + dx;
                        bf16x8 a = *(const bf16x8*)(&rp[(size_t)row * CPAD + ((kc * 4 + quad) ^ (row & 7)) * 8]);
#pragma unroll
                        for (int nl = 0; nl < 2; ++nl)
                            acc[ml][nl] = __builtin_amdgcn_mfma_f32_16x16x32_bf16(a, bf[kc][nl], acc[ml][nl], 0, 0, 0);
                    }
                }
            }
        }
        __syncthreads();
        p ^= 1;
    }

    const size_t vbase = ((size_t)z * 64 + y) * 64;
#pragma unroll
    for (int ml = 0; ml < 2; ++ml) {
#pragma unroll
        for (int nl = 0; nl < 2; ++nl) {
            const int oc = (nt2 + nl) * 16 + l16;
            const float bv = Bias[oc];
#pragma unroll
            for (int r = 0; r < 4; ++r)
                Out[(vbase + (mt2 + ml) * 16 + quad * 4 + r) * 64 + oc] = f2bf(acc[ml][nl][r] + bv);
        }
    }
}

// ---------------------------------------------------------------------------
// Per-channel sum / sumsq over all voxels (InstanceNorm stats).
// ---------------------------------------------------------------------------
__global__ __launch_bounds__(256) void stats_kernel(
        const unsigned short* __restrict__ H, float* __restrict__ stats) {
    const int t = threadIdx.x;
    const int c = t & 63, g = t >> 6;
    float s = 0.f, q = 0.f;
    for (int v = blockIdx.x * 4 + g; v < NVOX; v += gridDim.x * 4) {
        float x = bf2f(H[(size_t)v * 64 + c]);
        s += x; q = fmaf(x, x, q);
    }
    __shared__ float ls[256], lq[256];
    ls[t] = s; lq[t] = q;
    __syncthreads();
    if (t < 64) {
        s = ls[t] + ls[t + 64] + ls[t + 128] + ls[t + 192];
        q = lq[t] + lq[t + 64] + lq[t + 128] + lq[t + 192];
        atomicAdd(&stats[c], s);
        atomicAdd(&stats[64 + c], q);
    }
}

__global__ void finalize_kernel(const float* __restrict__ stats, float* __restrict__ musr) {
    int c = threadIdx.x;
    if (c < 64) {
        float mu  = stats[c] * (1.0f / 262144.0f);
        float var = stats[64 + c] * (1.0f / 262144.0f) - mu * mu;
        musr[c] = mu;
        musr[64 + c] = rsqrtf(var + 1e-5f);
    }
}

// ---------------------------------------------------------------------------
// Elementwise InstanceNorm + exact GELU, [v][64] -> [v][64] bf16
// ---------------------------------------------------------------------------
__global__ __launch_bounds__(256) void norm_gelu_kernel(
        const unsigned short* __restrict__ H, const float* __restrict__ musr,
        unsigned short* __restrict__ G) {
    const size_t base = ((size_t)blockIdx.x * 256 + threadIdx.x) * 8;
    uint4 u = *(const uint4*)(H + base);
    const int c0 = (int)(base & 63);
    const unsigned int uu[4] = {u.x, u.y, u.z, u.w};
    unsigned int w[4];
#pragma unroll
    for (int p = 0; p < 4; ++p) {
        int c = c0 + p * 2;
        float x0 = (bflo(uu[p]) - musr[c]) * musr[64 + c];
        float x1 = (bfhi(uu[p]) - musr[c + 1]) * musr[64 + c + 1];
        float g0 = 0.5f * x0 * (1.f + erff(x0 * 0.70710678118f));
        float g1 = 0.5f * x1 * (1.f + erff(x1 * 0.70710678118f));
        w[p] = (unsigned int)f2bf(g0) | ((unsigned int)f2bf(g1) << 16);
    }
    *(uint4*)(G + base) = make_uint4(w[0], w[1], w[2], w[3]);
}

// ---------------------------------------------------------------------------
// Final: InstanceNorm + exact GELU on h2, write fp32 channel planes [64][v].
// ---------------------------------------------------------------------------
__global__ __launch_bounds__(256) void out_final_kernel(
        const unsigned short* __restrict__ H2, const float* __restrict__ musr,
        float* __restrict__ OutEnc) {
    __shared__ float tile[64 * 260];
    const int t = threadIdx.x;
    const size_t v0 = (size_t)blockIdx.x * 256;
#pragma unroll
    for (int i = 0; i < 8; ++i) {
        int chunk = t + i * 256;                  // 0..2047
        uint4 u = *(const uint4*)(H2 + v0 * 64 + (size_t)chunk * 8);
        int vox = chunk >> 3;
        int c0 = (chunk & 7) * 8;
        const unsigned int uu[4] = {u.x, u.y, u.z, u.w};
#pragma unroll
        for (int p = 0; p < 4; ++p) {
            int c = c0 + p * 2;
            float x0 = (bflo(uu[p]) - musr[c]) * musr[64 + c];
            float x1 = (bfhi(uu[p]) - musr[c + 1]) * musr[64 + c + 1];
            tile[c * 260 + vox]       = 0.5f * x0 * (1.f + erff(x0 * 0.70710678118f));
            tile[(c + 1) * 260 + vox] = 0.5f * x1 * (1.f + erff(x1 * 0.70710678118f));
        }
    }
    __syncthreads();
    const int c = t >> 2, sub = t & 3;
#pragma unroll
    for (int iter = 0; iter < 16; ++iter) {
        int fq = iter * 4 + sub;                  // float4 index 0..63
        float4 val = *(const float4*)(&tile[c * 260 + fq * 4]);
        *(float4*)(OutEnc + (size_t)c * NVOX + v0 + fq * 4) = val;
    }
}

// ---------------------------------------------------------------------------
extern "C" void kernel_launch(void* const* d_in, const int* in_sizes, int n_in,
                              void* d_out, int out_size, void* d_ws, size_t ws_size,
                              hipStream_t stream) {
    const void* src  = d_in[0];
    const void* tgt  = d_in[1];
    const void* wsrc = d_in[2];
    const void* bsrc = d_in[3];
    const void* wtgt = d_in[4];
    const void* btgt = d_in[5];
    const void* w1   = d_in[6];
    const void* b1   = d_in[7];
    const void* w2   = d_in[8];
    const void* b2   = d_in[9];
    float* out = (float*)d_out;   // fp32 outputs, 70*262144 elements

    char* ws = (char*)d_ws;
    unsigned short* TPb = (unsigned short*)(ws);                  // 33,554,432 B
    unsigned short* SPb = (unsigned short*)(ws + 33554432);       // 33,554,432 B
    unsigned short* X1  = (unsigned short*)(ws + 67108864);       // 83,886,080 B
    unsigned short* Wf1 = (unsigned short*)(ws + 150994944);      // main+tail frags
    unsigned short* Wf2 = (unsigned short*)(ws + 151547904);      //    221,184 B
    int*   flag   = (int*)  (ws + 151769088);
    float* fbias  = (float*)(ws + 151769152);                     // 256 f32
    float* stats1 = (float*)(ws + 151770176);                     // 128 f32
    float* musr1  = (float*)(ws + 151770688);
    float* stats2 = (float*)(ws + 151771200);
    float* musr2  = (float*)(ws + 151771712);
    unsigned short* H1 = SPb;
    unsigned short* G1 = TPb;
    unsigned short* H2 = X1;
    unsigned short* Wf1e = Wf1 + 27 * 4 * 4 * 512;                // tail frags

    (void)hipMemsetAsync(stats1, 0, 2048, stream);
    sniff_kernel<<<1, 256, 0, stream>>>((const unsigned short*)src, flag);
    prep_kernel<<<1313, 256, 0, stream>>>(w1, w2, bsrc, btgt, b1, b2, flag, Wf1, Wf2, fbias);
    proj_kernel<<<dim3(1024, 2), 256, 0, stream>>>(src, tgt, wsrc, wtgt, fbias, flag, SPb, TPb);
    corr_kernel<<<4096, 256, 0, stream>>>(SPb, TPb, X1, out);
    conv3_kernel<160, 128, 4, 4, 4, true><<<4096, 256, 0, stream>>>(X1, Wf1, Wf1e, fbias + 128, H1);
    stats_kernel<<<256, 256, 0, stream>>>(H1, stats1);
    finalize_kernel<<<1, 64, 0, stream>>>(stats1, musr1);
    norm_gelu_kernel<<<8192, 256, 0, stream>>>(H1, musr1, G1);
    conv3_kernel<64, 64, 2, 2, 6, false><<<4096, 256, 0, stream>>>(G1, Wf2, nullptr, fbias + 192, H2);
    stats_kernel<<<256, 256, 0, stream>>>(H2, stats2);
    finalize_kernel<<<1, 64, 0, stream>>>(stats2, musr2);
    out_final_kernel<<<1024, 256, 0, stream>>>(H2, musr2, out + 6 * (size_t)NVOX);
}

// Round 6
// 707.220 us; speedup vs baseline: 1.0719x; 1.0719x over previous
//
#include <hip/hip_runtime.h>

#define DEV __device__ __forceinline__

typedef short bf16x8 __attribute__((ext_vector_type(8)));
typedef float f32x4 __attribute__((ext_vector_type(4)));

static const int NVOX = 262144; // 64^3

DEV float bflo(unsigned int u) { return __uint_as_float(u << 16); }
DEV float bfhi(unsigned int u) { return __uint_as_float(u & 0xffff0000u); }
DEV float bf2f(unsigned short s) { return __uint_as_float(((unsigned int)s) << 16); }
DEV unsigned short f2bf(float f) {
    unsigned int x = __float_as_uint(f);
    x += 0x7fffu + ((x >> 16) & 1u);   // RNE
    return (unsigned short)(x >> 16);
}
// dual-dtype raw-input load: f==1 -> fp32, f==0 -> bf16
DEV float ldin(const void* p, int i, int f) {
    return f ? ((const float*)p)[i] : bf2f(((const unsigned short*)p)[i]);
}

// async 16B global->LDS DMA. LDS dest = wave-uniform base + lane*16.
DEV void gld16(const unsigned short* g, unsigned short* l) {
    __builtin_amdgcn_global_load_lds(
        (const __attribute__((address_space(1))) unsigned int*)g,
        (__attribute__((address_space(3))) unsigned int*)l, 16, 0, 0);
}

// ---------------------------------------------------------------------------
// Dtype sniffer (insurance; fp32 inputs confirmed).
// ---------------------------------------------------------------------------
__global__ void sniff_kernel(const unsigned short* __restrict__ src, int* __restrict__ flag) {
    __shared__ int cnt[256];
    int t = threadIdx.x;
    int c = 0;
    for (int i = t; i < 4096; i += 256) {
        unsigned int u = (unsigned int)src[i] & 0x7fffu;
        c += (u >= 0x4900u) ? 1 : 0;
    }
    cnt[t] = c;
    __syncthreads();
    for (int s = 128; s > 0; s >>= 1) {
        if (t < s) cnt[t] += cnt[t + s];
        __syncthreads();
    }
    if (t == 0) *flag = (cnt[0] > 8) ? 1 : 0;
}

// ---------------------------------------------------------------------------
// Weight prep into MFMA B-fragment order (unchanged).
// ---------------------------------------------------------------------------
__global__ void prep_kernel(const void* __restrict__ w1, const void* __restrict__ w2,
                            const void* __restrict__ bsv, const void* __restrict__ btv,
                            const void* __restrict__ b1v, const void* __restrict__ b2v,
                            const int* __restrict__ flag,
                            unsigned short* __restrict__ Wf1,
                            unsigned short* __restrict__ Wf2,
                            float* __restrict__ fbias) {
    const int f = *flag;
    int idx = blockIdx.x * 256 + threadIdx.x;
    const int N1  = 27 * 4 * 4 * 512;   // 221184 (main, kc<4)
    const int N1E = 2 * 4 * 512;        //   4096 (tail)
    const int N2  = 27 * 2 * 4 * 512;   // 110592
    if (idx < N1) {
        int frag = idx >> 9;           // (tap*4 + kc)*4 + nt
        int r    = idx & 511;
        int lane = r >> 3, j = r & 7;
        int nt = frag & 3;
        int tk = frag >> 2;            // tap*4 + kc
        int tap = tk >> 2, kc = tk & 3;
        int o  = nt * 16 + (lane & 15);
        int cp = kc * 32 + (lane >> 4) * 8 + j;   // < 128 always
        Wf1[idx] = f2bf(ldin(w1, (o * 130 + cp) * 27 + tap, f));
    } else if (idx < N1 + N1E) {
        int i2 = idx - N1;
        int frag = i2 >> 9;            // kc*4 + nt (kc<2)
        int r    = i2 & 511;
        int lane = r >> 3, j = r & 7;
        int nt = frag & 3, kc = frag >> 2;
        int o   = nt * 16 + (lane & 15);
        int kap = kc * 32 + (lane >> 4) * 8 + j;  // kappa = tap*2 + ch
        unsigned short val = 0;
        if (kap < 54) {
            int tap = kap >> 1, ch = 128 + (kap & 1);
            val = f2bf(ldin(w1, (o * 130 + ch) * 27 + tap, f));
        }
        Wf1[idx] = val;                // Wf1e contiguous after Wf1
    } else if (idx < N1 + N1E + N2) {
        int i2 = idx - N1 - N1E;
        int frag = i2 >> 9;            // (tap*2 + kc)*4 + nt
        int r    = i2 & 511;
        int lane = r >> 3, j = r & 7;
        int nt = frag & 3;
        int tk = frag >> 2;
        int tap = tk >> 1, kc = tk & 1;
        int o = nt * 16 + (lane & 15);
        int c = kc * 32 + (lane >> 4) * 8 + j;
        Wf2[i2] = f2bf(ldin(w2, (o * 64 + c) * 27 + tap, f));
    } else if (idx < N1 + N1E + N2 + 256) {
        int j = idx - N1 - N1E - N2;
        const void* bp = (j < 64) ? bsv : (j < 128) ? btv : (j < 192) ? b1v : b2v;
        fbias[j] = ldin(bp, j & 63, f);
    }
}

// ---------------------------------------------------------------------------
// Projection (1x1x1 conv 32->64) + L2 normalize over channels.
// ---------------------------------------------------------------------------
__global__ __launch_bounds__(256) void proj_kernel(
        const void* __restrict__ Xsrc, const void* __restrict__ Xtgt,
        const void* __restrict__ Wsrc, const void* __restrict__ Wtgt,
        const float* __restrict__ fbias, const int* __restrict__ flag,
        unsigned short* __restrict__ SP, unsigned short* __restrict__ TP) {
    const int f = *flag;
    const void* Xin = blockIdx.y ? Xtgt : Xsrc;
    const void* W   = blockIdx.y ? Wtgt : Wsrc;
    const float* Bb = fbias + (blockIdx.y ? 64 : 0);
    unsigned short* Outp = blockIdx.y ? TP : SP;

    __shared__ float ws[2048];   // [ci][o]
    const int t = threadIdx.x;
    for (int i = t; i < 2048; i += 256) {
        int ci = i >> 6, o = i & 63;
        ws[i] = ldin(W, o * 32 + ci, f);
    }
    __syncthreads();

    const size_t v = (size_t)blockIdx.x * 256 + t;
    float acc[64];
#pragma unroll
    for (int o = 0; o < 64; ++o) acc[o] = Bb[o];
    if (f) {
        const float* Xf = (const float*)Xin;
        for (int ci = 0; ci < 32; ++ci) {
            float x = Xf[(size_t)ci * NVOX + v];
            const float4* wr = (const float4*)(ws + ci * 64);
#pragma unroll
            for (int o4 = 0; o4 < 16; ++o4) {
                float4 w4 = wr[o4];
                acc[o4 * 4 + 0] = fmaf(w4.x, x, acc[o4 * 4 + 0]);
                acc[o4 * 4 + 1] = fmaf(w4.y, x, acc[o4 * 4 + 1]);
                acc[o4 * 4 + 2] = fmaf(w4.z, x, acc[o4 * 4 + 2]);
                acc[o4 * 4 + 3] = fmaf(w4.w, x, acc[o4 * 4 + 3]);
            }
        }
    } else {
        const unsigned short* Xb = (const unsigned short*)Xin;
        for (int ci = 0; ci < 32; ++ci) {
            float x = bf2f(Xb[(size_t)ci * NVOX + v]);
            const float4* wr = (const float4*)(ws + ci * 64);
#pragma unroll
            for (int o4 = 0; o4 < 16; ++o4) {
                float4 w4 = wr[o4];
                acc[o4 * 4 + 0] = fmaf(w4.x, x, acc[o4 * 4 + 0]);
                acc[o4 * 4 + 1] = fmaf(w4.y, x, acc[o4 * 4 + 1]);
                acc[o4 * 4 + 2] = fmaf(w4.z, x, acc[o4 * 4 + 2]);
                acc[o4 * 4 + 3] = fmaf(w4.w, x, acc[o4 * 4 + 3]);
            }
        }
    }
    float s = 0.f;
#pragma unroll
    for (int o = 0; o < 64; ++o) s = fmaf(acc[o], acc[o], s);
    float scale = 1.f / fmaxf(sqrtf(s), 1e-12f);

    unsigned int pk[32];
#pragma unroll
    for (int o = 0; o < 32; ++o)
        pk[o] = (unsigned int)f2bf(acc[2 * o] * scale) |
                ((unsigned int)f2bf(acc[2 * o + 1] * scale) << 16);
    uint4* outp = (uint4*)(Outp + v * 64);
#pragma unroll
    for (int j = 0; j < 8; ++j)
        outp[j] = make_uint4(pk[4 * j], pk[4 * j + 1], pk[4 * j + 2], pk[4 * j + 3]);
}

// ---------------------------------------------------------------------------
// Correlation via MFMA (banded implicit GEMM) — unchanged from R5.
// ---------------------------------------------------------------------------
__global__ __launch_bounds__(256) void corr_kernel(
        const unsigned short* __restrict__ SP, const unsigned short* __restrict__ TP,
        unsigned short* __restrict__ X1, float* __restrict__ Out) {
    __shared__ __align__(16) unsigned short tpb[2][80 * 64];   // 20480 B
    __shared__ __align__(16) unsigned short stage[64 * 128];   // 16384 B

    const int t = threadIdx.x;
    const int wv = t >> 6, lane = t & 63;
    const int q = lane >> 4, l16 = lane & 15;
    const int x0 = wv * 16;

    const int bid = blockIdx.x;
    const int wg = (bid & 7) * 512 + (bid >> 3);
    const int z = wg >> 6, y = wg & 63;
    const size_t vbase = ((size_t)z * 64 + y) * 64;

    const unsigned short* arow = SP + (vbase + x0 + l16) * 64 + q * 8;
    const bf16x8 a0 = *(const bf16x8*)(arow);
    const bf16x8 a1 = *(const bf16x8*)(arow + 32);

    auto stage_tp = [&](int it, int b) {
        const int zc = min(max(z + it / 5 - 2, 0), 63);
        const int yc = min(max(y + it % 5 - 2, 0), 63);
        const unsigned short* tb = TP + ((size_t)zc * 64 + yc) * 4096;
#pragma unroll
        for (int j = 0; j < 2; ++j) {
            int c = t + j * 256;
            int pp = c >> 3, cc = c & 7;
            int xc = min(max(pp - 2, 0), 63);
            gld16(tb + xc * 64 + ((cc ^ (pp & 7)) * 8),
                  &tpb[b][(wv * 64 + j * 256) * 8]);
        }
        if (wv < 2) {
            int c = 512 + wv * 64 + lane;
            int pp = c >> 3, cc = c & 7;
            int xc = min(max(pp - 2, 0), 63);
            gld16(tb + xc * 64 + ((cc ^ (pp & 7)) * 8),
                  &tpb[b][(512 + wv * 64) * 8]);
        }
    };

    stage_tp(0, 0);
    __syncthreads();

    int p = 0;
    for (int it = 0; it < 25; ++it) {
        if (it < 24) stage_tp(it + 1, p ^ 1);   // DMA overlaps compute below

        f32x4 acc[2] = {{0.f, 0.f, 0.f, 0.f}, {0.f, 0.f, 0.f, 0.f}};
        {
            const char* tb = (const char*)tpb[p];
#pragma unroll
            for (int nt = 0; nt < 2; ++nt) {
                const int pr = x0 + nt * 16 + l16;
                bf16x8 b0 = *(const bf16x8*)(tb + pr * 128 + ((q ^ (pr & 7)) * 16));
                bf16x8 b1 = *(const bf16x8*)(tb + pr * 128 + (((4 + q) ^ (pr & 7)) * 16));
                acc[nt] = __builtin_amdgcn_mfma_f32_16x16x32_bf16(a0, b0, acc[nt], 0, 0, 0);
                acc[nt] = __builtin_amdgcn_mfma_f32_16x16x32_bf16(a1, b1, acc[nt], 0, 0, 0);
            }
        }
        const int kb = it * 5;
        char* sg = (char*)stage;
#pragma unroll
        for (int nt = 0; nt < 2; ++nt) {
#pragma unroll
            for (int r = 0; r < 4; ++r) {
                int ml = q * 4 + r;
                int dxp = nt * 16 + l16 - ml;     // dx + 2
                if ((unsigned)dxp < 5u) {
                    int xl = x0 + ml;
                    *(unsigned short*)(sg + xl * 256 + (((kb + dxp) * 2) ^ ((xl & 7) << 4))) =
                        f2bf(acc[nt][r]);
                }
            }
        }
        __syncthreads();
        p ^= 1;
    }

    // ---- deferred softmax tail: 4 lanes per voxel, all 256 threads ----
    {
        const int vox = t >> 2, part = t & 3;
        const int sx = (vox & 7) << 4;
        const char* sg = (const char*)stage;
        uint4 u[4];
#pragma unroll
        for (int j = 0; j < 4; ++j)
            u[j] = *(const uint4*)(sg + vox * 256 + ((part * 64 + j * 16) ^ sx));

        float m = -1e30f, s2 = -1e30f;
#pragma unroll
        for (int j = 0; j < 4; ++j) {
            const unsigned int uu[4] = {u[j].x, u[j].y, u[j].z, u[j].w};
#pragma unroll
            for (int w = 0; w < 4; ++w) {
                int k = part * 32 + j * 8 + w * 2;
                float d0 = (k < 125) ? bflo(uu[w]) : -1e30f;
                float d1 = (k + 1 < 125) ? bfhi(uu[w]) : -1e30f;
                float lo0 = fminf(d0, m); m = fmaxf(d0, m); s2 = fmaxf(s2, lo0);
                float lo1 = fminf(d1, m); m = fmaxf(d1, m); s2 = fmaxf(s2, lo1);
            }
        }
#pragma unroll
        for (int off = 1; off <= 2; off <<= 1) {
            float om = __shfl_xor(m, off, 64);
            float os = __shfl_xor(s2, off, 64);
            float lo = fminf(m, om);
            m = fmaxf(m, om);
            s2 = fmaxf(fmaxf(s2, os), lo);
        }
        int kk = part * 32;
        int dz0 = kk / 25, rem = kk - dz0 * 25, dy0 = rem / 5, dx0 = rem - dy0 * 5;
        float fx = (float)(dx0 - 2), fy = (float)(dy0 - 2), fz = (float)(dz0 - 2);
        float Zs = 0.f, S1 = 0.f, Ox = 0.f, Oy = 0.f, Oz = 0.f;
#pragma unroll
        for (int j = 0; j < 4; ++j) {
            const unsigned int uu[4] = {u[j].x, u[j].y, u[j].z, u[j].w};
#pragma unroll
            for (int w = 0; w < 8; ++w) {
                int k = part * 32 + j * 8 + w;
                bool ok = (k < 125);
                float d = (w & 1) ? bfhi(uu[w >> 1]) : bflo(uu[w >> 1]);
                d = ok ? d : 0.f;                 // sanitize: garbage slot may be NaN
                float e = ok ? __expf(d - m) : 0.f;
                Zs += e; S1 = fmaf(e, d, S1);
                Ox = fmaf(e, fx, Ox); Oy = fmaf(e, fy, Oy); Oz = fmaf(e, fz, Oz);
                fx += 1.f;
                if (fx > 2.5f) { fx = -2.f; fy += 1.f; if (fy > 2.5f) { fy = -2.f; fz += 1.f; } }
            }
        }
#pragma unroll
        for (int off = 1; off <= 2; off <<= 1) {
            Zs += __shfl_xor(Zs, off, 64);
            S1 += __shfl_xor(S1, off, 64);
            Ox += __shfl_xor(Ox, off, 64);
            Oy += __shfl_xor(Oy, off, 64);
            Oz += __shfl_xor(Oz, off, 64);
        }
        if (part == 0) {
            float inv  = 1.f / fmaxf(Zs, 1e-8f);
            float eoz = Oz * inv, eoy = Oy * inv, eox = Ox * inv;
            float conf = fminf(inv, 1.f);
            float marg = fmaxf(conf - __expf(s2 - m) * inv, 0.f);
            float ent  = m + __logf(fmaxf(Zs, 1e-8f)) - S1 * inv;
            char* sgw = (char*)stage;
            *(unsigned short*)(sgw + vox * 256 + (250 ^ sx)) = f2bf(eoz);
            *(unsigned short*)(sgw + vox * 256 + (252 ^ sx)) = f2bf(eoy);
            *(unsigned short*)(sgw + vox * 256 + (254 ^ sx)) = f2bf(eox);
            const size_t v = vbase + vox;
            *(unsigned int*)(X1 + v * 160 + 128) =
                (unsigned int)f2bf(conf) | ((unsigned int)f2bf(ent) << 16);
            Out[v]                    = eoz;
            Out[(size_t)NVOX + v]     = eoy;
            Out[(size_t)2 * NVOX + v] = eox;
            Out[(size_t)3 * NVOX + v] = conf;
            Out[(size_t)4 * NVOX + v] = marg;
            Out[(size_t)5 * NVOX + v] = ent;
        }
    }
    __syncthreads();

#pragma unroll
    for (int j = 0; j < 4; ++j) {
        int i = t + j * 256;
        int vox = i >> 4, cc = i & 15;
        *(uint4*)(X1 + (vbase + vox) * 160 + (size_t)cc * 8) =
            *(const uint4*)((const char*)stage + vox * 256 + ((cc * 16) ^ ((vox & 7) << 4)));
    }
}

// ---------------------------------------------------------------------------
// 3x3x3 conv v3: block = TWO y-rows (128 voxels x 64 oc), tap-major loop so
// each weight fragment feeds both rows -> L2 weight traffic halved (was the
// dominant cost: ~103 us of conv1's 171). Plane ring = 3 LDS slots, DMA
// staging (pre-swizzled source, linear dest, XOR-swizzled reads). Static
// schedule: planes p=0..11 (p = (dz+1)*4 + (py-y+1)); compute iter i uses
// planes s0=(i/3)*4+i%3 and s0+1; prefetch s0+2 during compute except at
// dz-group entries (i=3,6) which pre-stage {s0+1,s0+2} + drain barrier.
// Slot-reuse safety verified by enumeration (each slot's prior plane is
// dead >= 1 barrier before overwrite).
// ---------------------------------------------------------------------------
template <int XSTRIDE, int CPAD, int KC, int NLD, int MINW, bool TAIL>
__global__ __launch_bounds__(256, MINW) void conv3_kernel(
        const unsigned short* __restrict__ Xin, const unsigned short* __restrict__ Wf,
        const unsigned short* __restrict__ Wfe,
        const float* __restrict__ Bias, unsigned short* __restrict__ Out) {
    constexpr int SLOT = 66 * CPAD;
    constexpr int CH16 = CPAD / 8;
    __shared__ __align__(16) unsigned short lds[3 * SLOT];
    const int lin = blockIdx.x;
    const int wg = (lin & 7) * 256 + (lin >> 3);   // 2048 = 8*256, bijective
    const int z = wg >> 5;
    const int y = (wg & 31) * 2;
    const int t = threadIdx.x;
    const int wv = t >> 6, lane = t & 63;
    const int quad = lane >> 4, l16 = lane & 15;
    const int ml2 = (wv & 1) * 2;    // m-tile pair within each row
    const int nt2 = (wv >> 1) * 2;   // n-tile pair

    f32x4 acc[2][2][2] = {};         // [row][ml][nl]

    auto stage_plane = [&](int pidx) {
        const int zz = z + (pidx >> 2) - 1;
        const int py = y + (pidx & 3) - 1;
        if ((unsigned)zz >= 64u || (unsigned)py >= 64u) return;
        const unsigned short* base = Xin + (((size_t)zz * 64 + py) * 64) * XSTRIDE;
        unsigned short* dst = lds + (pidx % 3) * SLOT + CPAD;
#pragma unroll
        for (int i = 0; i < NLD; ++i) {
            int chunk = wv * 64 + lane + i * 256;    // 0 .. 64*CH16-1
            int xi = chunk / CH16;                   // global x (LDS row xi+1)
            int cc = chunk % CH16;
            gld16(base + xi * XSTRIDE + ((cc ^ ((xi + 1) & 7)) * 8),
                  dst + (size_t)(wv * 64 + i * 256) * 8);
        }
    };

    if (TAIL) {
        // im2col gather of ch 128/129 neighborhoods for BOTH rows into lds
        // scratch: ebuf[vox<128][kappa], kappa = tap*2 + ch, stride 72 shorts.
        unsigned short* ebuf = lds;
#pragma unroll
        for (int i2 = 0; i2 < 16; ++i2) {
            int i = t + i2 * 256;                 // 0..4095
            int vox = i >> 5, slot = i & 31;
            unsigned int val = 0u;
            int kap;
            if (slot < 27) {
                int ddz = slot / 9 - 1, ddy = (slot / 3) % 3 - 1, dxx = slot % 3 - 1;
                int zz = z + ddz, yy = y + (vox >> 6) + ddy, xx = (vox & 63) + dxx;
                kap = slot * 2;
                if ((unsigned)zz < 64u && (unsigned)yy < 64u && (unsigned)xx < 64u)
                    val = *(const unsigned int*)(Xin + (((size_t)zz * 64 + yy) * 64 + xx) * XSTRIDE + 128);
            } else {
                kap = 54 + (slot - 27) * 2;       // zero-fill kappa 54..63
            }
            *(unsigned int*)(ebuf + (size_t)vox * 72 + kap) = val;
        }
        __syncthreads();
#pragma unroll
        for (int kc = 0; kc < 2; ++kc) {
            bf16x8 bte[2];
#pragma unroll
            for (int nl = 0; nl < 2; ++nl)
                bte[nl] = *(const bf16x8*)(Wfe + (size_t)(kc * 4 + nt2 + nl) * 512 + lane * 8);
#pragma unroll
            for (int r = 0; r < 2; ++r)
#pragma unroll
            for (int ml = 0; ml < 2; ++ml) {
                bf16x8 a = *(const bf16x8*)(ebuf + (size_t)(r * 64 + (ml2 + ml) * 16 + l16) * 72 + (kc * 4 + quad) * 8);
#pragma unroll
                for (int nl = 0; nl < 2; ++nl)
                    acc[r][ml][nl] = __builtin_amdgcn_mfma_f32_16x16x32_bf16(a, bte[nl], acc[r][ml][nl], 0, 0, 0);
            }
        }
        __syncthreads();   // ebuf reads drained before slot staging overwrites
    }

    // zero halo rows 0 and 65 of all 3 slots (x = -1/64: always outside)
    if (t < 6 * CH16) {
        int sl = t / (2 * CH16), r2 = (t / CH16) & 1, c = t % CH16;
        *(uint4*)(&lds[(size_t)sl * SLOT + (size_t)(r2 * 65) * CPAD + c * 8]) =
            make_uint4(0u, 0u, 0u, 0u);
    }
    stage_plane(0);
    stage_plane(1);
    __syncthreads();   // drains DMA + halo zeros

    for (int i = 0; i < 9; ++i) {
        const int s0 = (i / 3) * 4 + i % 3;
        if (i == 3 || i == 6) {
            // dz-group entry: both planes of the new group not yet staged
            stage_plane(s0 + 1);
            stage_plane(s0 + 2);
            __syncthreads();
        } else if (s0 + 2 < 12) {
            stage_plane(s0 + 2);   // prefetch, drained by this iter's barrier
        }

        const int zz = z + i / 3 - 1;
        const int dy = i % 3 - 1;
        const bool zok = (unsigned)zz < 64u;
        const bool rok0 = zok && (unsigned)(y + dy) < 64u;
        const bool rok1 = zok && (unsigned)(y + 1 + dy) < 64u;
        const unsigned short* sb0 = lds + (size_t)(s0 % 3) * SLOT;
        const unsigned short* sb1 = lds + (size_t)((s0 + 1) % 3) * SLOT;
        if (rok0 || rok1) {
#pragma unroll
            for (int dx = 0; dx < 3; ++dx) {
                const int tap = (i / 3) * 9 + (i % 3) * 3 + dx;
                const unsigned short* wt = Wf + ((size_t)tap * KC * 4) * 512 + lane * 8;
                bf16x8 bf[KC][2];
#pragma unroll
                for (int kc = 0; kc < KC; ++kc)
#pragma unroll
                    for (int nl = 0; nl < 2; ++nl)
                        bf[kc][nl] = *(const bf16x8*)(wt + (size_t)(kc * 4 + nt2 + nl) * 512);
#pragma unroll
                for (int kc = 0; kc < KC; ++kc) {
#pragma unroll
                    for (int ml = 0; ml < 2; ++ml) {
                        const int row = (ml2 + ml) * 16 + l16 + dx;
                        const int co = ((kc * 4 + quad) ^ (row & 7)) * 8;
                        if (rok0) {
                            bf16x8 a = *(const bf16x8*)(&sb0[(size_t)row * CPAD + co]);
#pragma unroll
                            for (int nl = 0; nl < 2; ++nl)
                                acc[0][ml][nl] = __builtin_amdgcn_mfma_f32_16x16x32_bf16(a, bf[kc][nl], acc[0][ml][nl], 0, 0, 0);
                        }
                        if (rok1) {
                            bf16x8 a = *(const bf16x8*)(&sb1[(size_t)row * CPAD + co]);
#pragma unroll
                            for (int nl = 0; nl < 2; ++nl)
                                acc[1][ml][nl] = __builtin_amdgcn_mfma_f32_16x16x32_bf16(a, bf[kc][nl], acc[1][ml][nl], 0, 0, 0);
                        }
                    }
                }
            }
        }
        __syncthreads();
    }

#pragma unroll
    for (int r = 0; r < 2; ++r) {
        const size_t vb = ((size_t)z * 64 + (y + r)) * 64;
#pragma unroll
        for (int ml = 0; ml < 2; ++ml) {
#pragma unroll
            for (int nl = 0; nl < 2; ++nl) {
                const int oc = (nt2 + nl) * 16 + l16;
                const float bv = Bias[oc];
#pragma unroll
                for (int rr = 0; rr < 4; ++rr)
                    Out[(vb + (ml2 + ml) * 16 + quad * 4 + rr) * 64 + oc] =
                        f2bf(acc[r][ml][nl][rr] + bv);
            }
        }
    }
}

// ---------------------------------------------------------------------------
// Per-channel sum / sumsq over all voxels (InstanceNorm stats).
// ---------------------------------------------------------------------------
__global__ __launch_bounds__(256) void stats_kernel(
        const unsigned short* __restrict__ H, float* __restrict__ stats) {
    const int t = threadIdx.x;
    const int c = t & 63, g = t >> 6;
    float s = 0.f, q = 0.f;
    for (int v = blockIdx.x * 4 + g; v < NVOX; v += gridDim.x * 4) {
        float x = bf2f(H[(size_t)v * 64 + c]);
        s += x; q = fmaf(x, x, q);
    }
    __shared__ float ls[256], lq[256];
    ls[t] = s; lq[t] = q;
    __syncthreads();
    if (t < 64) {
        s = ls[t] + ls[t + 64] + ls[t + 128] + ls[t + 192];
        q = lq[t] + lq[t + 64] + lq[t + 128] + lq[t + 192];
        atomicAdd(&stats[c], s);
        atomicAdd(&stats[64 + c], q);
    }
}

__global__ void finalize_kernel(const float* __restrict__ stats, float* __restrict__ musr) {
    int c = threadIdx.x;
    if (c < 64) {
        float mu  = stats[c] * (1.0f / 262144.0f);
        float var = stats[64 + c] * (1.0f / 262144.0f) - mu * mu;
        musr[c] = mu;
        musr[64 + c] = rsqrtf(var + 1e-5f);
    }
}

// ---------------------------------------------------------------------------
// Elementwise InstanceNorm + exact GELU, [v][64] -> [v][64] bf16
// ---------------------------------------------------------------------------
__global__ __launch_bounds__(256) void norm_gelu_kernel(
        const unsigned short* __restrict__ H, const float* __restrict__ musr,
        unsigned short* __restrict__ G) {
    const size_t base = ((size_t)blockIdx.x * 256 + threadIdx.x) * 8;
    uint4 u = *(const uint4*)(H + base);
    const int c0 = (int)(base & 63);
    const unsigned int uu[4] = {u.x, u.y, u.z, u.w};
    unsigned int w[4];
#pragma unroll
    for (int p = 0; p < 4; ++p) {
        int c = c0 + p * 2;
        float x0 = (bflo(uu[p]) - musr[c]) * musr[64 + c];
        float x1 = (bfhi(uu[p]) - musr[c + 1]) * musr[64 + c + 1];
        float g0 = 0.5f * x0 * (1.f + erff(x0 * 0.70710678118f));
        float g1 = 0.5f * x1 * (1.f + erff(x1 * 0.70710678118f));
        w[p] = (unsigned int)f2bf(g0) | ((unsigned int)f2bf(g1) << 16);
    }
    *(uint4*)(G + base) = make_uint4(w[0], w[1], w[2], w[3]);
}

// ---------------------------------------------------------------------------
// Final: InstanceNorm + exact GELU on h2, write fp32 channel planes [64][v].
// ---------------------------------------------------------------------------
__global__ __launch_bounds__(256) void out_final_kernel(
        const unsigned short* __restrict__ H2, const float* __restrict__ musr,
        float* __restrict__ OutEnc) {
    __shared__ float tile[64 * 260];
    const int t = threadIdx.x;
    const size_t v0 = (size_t)blockIdx.x * 256;
#pragma unroll
    for (int i = 0; i < 8; ++i) {
        int chunk = t + i * 256;                  // 0..2047
        uint4 u = *(const uint4*)(H2 + v0 * 64 + (size_t)chunk * 8);
        int vox = chunk >> 3;
        int c0 = (chunk & 7) * 8;
        const unsigned int uu[4] = {u.x, u.y, u.z, u.w};
#pragma unroll
        for (int p = 0; p < 4; ++p) {
            int c = c0 + p * 2;
            float x0 = (bflo(uu[p]) - musr[c]) * musr[64 + c];
            float x1 = (bfhi(uu[p]) - musr[c + 1]) * musr[64 + c + 1];
            tile[c * 260 + vox]       = 0.5f * x0 * (1.f + erff(x0 * 0.70710678118f));
            tile[(c + 1) * 260 + vox] = 0.5f * x1 * (1.f + erff(x1 * 0.70710678118f));
        }
    }
    __syncthreads();
    const int c = t >> 2, sub = t & 3;
#pragma unroll
    for (int iter = 0; iter < 16; ++iter) {
        int fq = iter * 4 + sub;                  // float4 index 0..63
        float4 val = *(const float4*)(&tile[c * 260 + fq * 4]);
        *(float4*)(OutEnc + (size_t)c * NVOX + v0 + fq * 4) = val;
    }
}

// ---------------------------------------------------------------------------
extern "C" void kernel_launch(void* const* d_in, const int* in_sizes, int n_in,
                              void* d_out, int out_size, void* d_ws, size_t ws_size,
                              hipStream_t stream) {
    const void* src  = d_in[0];
    const void* tgt  = d_in[1];
    const void* wsrc = d_in[2];
    const void* bsrc = d_in[3];
    const void* wtgt = d_in[4];
    const void* btgt = d_in[5];
    const void* w1   = d_in[6];
    const void* b1   = d_in[7];
    const void* w2   = d_in[8];
    const void* b2   = d_in[9];
    float* out = (float*)d_out;   // fp32 outputs, 70*262144 elements

    char* ws = (char*)d_ws;
    unsigned short* TPb = (unsigned short*)(ws);                  // 33,554,432 B
    unsigned short* SPb = (unsigned short*)(ws + 33554432);       // 33,554,432 B
    unsigned short* X1  = (unsigned short*)(ws + 67108864);       // 83,886,080 B
    unsigned short* Wf1 = (unsigned short*)(ws + 150994944);      // main+tail frags
    unsigned short* Wf2 = (unsigned short*)(ws + 151547904);      //    221,184 B
    int*   flag   = (int*)  (ws + 151769088);
    float* fbias  = (float*)(ws + 151769152);                     // 256 f32
    float* stats1 = (float*)(ws + 151770176);                     // 128 f32
    float* musr1  = (float*)(ws + 151770688);
    float* stats2 = (float*)(ws + 151771200);
    float* musr2  = (float*)(ws + 151771712);
    unsigned short* H1 = SPb;
    unsigned short* G1 = TPb;
    unsigned short* H2 = X1;
    unsigned short* Wf1e = Wf1 + 27 * 4 * 4 * 512;                // tail frags

    (void)hipMemsetAsync(stats1, 0, 2048, stream);
    sniff_kernel<<<1, 256, 0, stream>>>((const unsigned short*)src, flag);
    prep_kernel<<<1313, 256, 0, stream>>>(w1, w2, bsrc, btgt, b1, b2, flag, Wf1, Wf2, fbias);
    proj_kernel<<<dim3(1024, 2), 256, 0, stream>>>(src, tgt, wsrc, wtgt, fbias, flag, SPb, TPb);
    corr_kernel<<<4096, 256, 0, stream>>>(SPb, TPb, X1, out);
    conv3_kernel<160, 128, 4, 4, 3, true><<<2048, 256, 0, stream>>>(X1, Wf1, Wf1e, fbias + 128, H1);
    stats_kernel<<<256, 256, 0, stream>>>(H1, stats1);
    finalize_kernel<<<1, 64, 0, stream>>>(stats1, musr1);
    norm_gelu_kernel<<<8192, 256, 0, stream>>>(H1, musr1, G1);
    conv3_kernel<64, 64, 2, 2, 4, false><<<2048, 256, 0, stream>>>(G1, Wf2, nullptr, fbias + 192, H2);
    stats_kernel<<<256, 256, 0, stream>>>(H2, stats2);
    finalize_kernel<<<1, 64, 0, stream>>>(stats2, musr2);
    out_final_kernel<<<1024, 256, 0, stream>>>(H2, musr2, out + 6 * (size_t)NVOX);
}

// Round 7
// 695.184 us; speedup vs baseline: 1.0904x; 1.0173x over previous
//
#include <hip/hip_runtime.h>

#define DEV __device__ __forceinline__

typedef short bf16x8 __attribute__((ext_vector_type(8)));
typedef float f32x4 __attribute__((ext_vector_type(4)));

static const int NVOX = 262144; // 64^3

DEV float bflo(unsigned int u) { return __uint_as_float(u << 16); }
DEV float bfhi(unsigned int u) { return __uint_as_float(u & 0xffff0000u); }
DEV float bf2f(unsigned short s) { return __uint_as_float(((unsigned int)s) << 16); }
DEV unsigned short f2bf(float f) {
    unsigned int x = __float_as_uint(f);
    x += 0x7fffu + ((x >> 16) & 1u);   // RNE
    return (unsigned short)(x >> 16);
}
// dual-dtype raw-input load: f==1 -> fp32, f==0 -> bf16
DEV float ldin(const void* p, int i, int f) {
    return f ? ((const float*)p)[i] : bf2f(((const unsigned short*)p)[i]);
}

// async 16B global->LDS DMA. LDS dest = wave-uniform base + lane*16.
DEV void gld16(const unsigned short* g, unsigned short* l) {
    __builtin_amdgcn_global_load_lds(
        (const __attribute__((address_space(1))) unsigned int*)g,
        (__attribute__((address_space(3))) unsigned int*)l, 16, 0, 0);
}

// ---------------------------------------------------------------------------
// Dtype sniffer (insurance; fp32 inputs confirmed).
// ---------------------------------------------------------------------------
__global__ void sniff_kernel(const unsigned short* __restrict__ src, int* __restrict__ flag) {
    __shared__ int cnt[256];
    int t = threadIdx.x;
    int c = 0;
    for (int i = t; i < 4096; i += 256) {
        unsigned int u = (unsigned int)src[i] & 0x7fffu;
        c += (u >= 0x4900u) ? 1 : 0;
    }
    cnt[t] = c;
    __syncthreads();
    for (int s = 128; s > 0; s >>= 1) {
        if (t < s) cnt[t] += cnt[t + s];
        __syncthreads();
    }
    if (t == 0) *flag = (cnt[0] > 8) ? 1 : 0;
}

// ---------------------------------------------------------------------------
// Weight prep into MFMA B-fragment order (unchanged).
// ---------------------------------------------------------------------------
__global__ void prep_kernel(const void* __restrict__ w1, const void* __restrict__ w2,
                            const void* __restrict__ bsv, const void* __restrict__ btv,
                            const void* __restrict__ b1v, const void* __restrict__ b2v,
                            const int* __restrict__ flag,
                            unsigned short* __restrict__ Wf1,
                            unsigned short* __restrict__ Wf2,
                            float* __restrict__ fbias) {
    const int f = *flag;
    int idx = blockIdx.x * 256 + threadIdx.x;
    const int N1  = 27 * 4 * 4 * 512;   // 221184 (main, kc<4)
    const int N1E = 2 * 4 * 512;        //   4096 (tail)
    const int N2  = 27 * 2 * 4 * 512;   // 110592
    if (idx < N1) {
        int frag = idx >> 9;           // (tap*4 + kc)*4 + nt
        int r    = idx & 511;
        int lane = r >> 3, j = r & 7;
        int nt = frag & 3;
        int tk = frag >> 2;            // tap*4 + kc
        int tap = tk >> 2, kc = tk & 3;
        int o  = nt * 16 + (lane & 15);
        int cp = kc * 32 + (lane >> 4) * 8 + j;   // < 128 always
        Wf1[idx] = f2bf(ldin(w1, (o * 130 + cp) * 27 + tap, f));
    } else if (idx < N1 + N1E) {
        int i2 = idx - N1;
        int frag = i2 >> 9;            // kc*4 + nt (kc<2)
        int r    = i2 & 511;
        int lane = r >> 3, j = r & 7;
        int nt = frag & 3, kc = frag >> 2;
        int o   = nt * 16 + (lane & 15);
        int kap = kc * 32 + (lane >> 4) * 8 + j;  // kappa = tap*2 + ch
        unsigned short val = 0;
        if (kap < 54) {
            int tap = kap >> 1, ch = 128 + (kap & 1);
            val = f2bf(ldin(w1, (o * 130 + ch) * 27 + tap, f));
        }
        Wf1[idx] = val;                // Wf1e contiguous after Wf1
    } else if (idx < N1 + N1E + N2) {
        int i2 = idx - N1 - N1E;
        int frag = i2 >> 9;            // (tap*2 + kc)*4 + nt
        int r    = i2 & 511;
        int lane = r >> 3, j = r & 7;
        int nt = frag & 3;
        int tk = frag >> 2;
        int tap = tk >> 1, kc = tk & 1;
        int o = nt * 16 + (lane & 15);
        int c = kc * 32 + (lane >> 4) * 8 + j;
        Wf2[i2] = f2bf(ldin(w2, (o * 64 + c) * 27 + tap, f));
    } else if (idx < N1 + N1E + N2 + 256) {
        int j = idx - N1 - N1E - N2;
        const void* bp = (j < 64) ? bsv : (j < 128) ? btv : (j < 192) ? b1v : b2v;
        fbias[j] = ldin(bp, j & 63, f);
    }
}

// ---------------------------------------------------------------------------
// Projection (1x1x1 conv 32->64) + L2 normalize over channels.
// ---------------------------------------------------------------------------
__global__ __launch_bounds__(256) void proj_kernel(
        const void* __restrict__ Xsrc, const void* __restrict__ Xtgt,
        const void* __restrict__ Wsrc, const void* __restrict__ Wtgt,
        const float* __restrict__ fbias, const int* __restrict__ flag,
        unsigned short* __restrict__ SP, unsigned short* __restrict__ TP) {
    const int f = *flag;
    const void* Xin = blockIdx.y ? Xtgt : Xsrc;
    const void* W   = blockIdx.y ? Wtgt : Wsrc;
    const float* Bb = fbias + (blockIdx.y ? 64 : 0);
    unsigned short* Outp = blockIdx.y ? TP : SP;

    __shared__ float ws[2048];   // [ci][o]
    const int t = threadIdx.x;
    for (int i = t; i < 2048; i += 256) {
        int ci = i >> 6, o = i & 63;
        ws[i] = ldin(W, o * 32 + ci, f);
    }
    __syncthreads();

    const size_t v = (size_t)blockIdx.x * 256 + t;
    float acc[64];
#pragma unroll
    for (int o = 0; o < 64; ++o) acc[o] = Bb[o];
    if (f) {
        const float* Xf = (const float*)Xin;
        for (int ci = 0; ci < 32; ++ci) {
            float x = Xf[(size_t)ci * NVOX + v];
            const float4* wr = (const float4*)(ws + ci * 64);
#pragma unroll
            for (int o4 = 0; o4 < 16; ++o4) {
                float4 w4 = wr[o4];
                acc[o4 * 4 + 0] = fmaf(w4.x, x, acc[o4 * 4 + 0]);
                acc[o4 * 4 + 1] = fmaf(w4.y, x, acc[o4 * 4 + 1]);
                acc[o4 * 4 + 2] = fmaf(w4.z, x, acc[o4 * 4 + 2]);
                acc[o4 * 4 + 3] = fmaf(w4.w, x, acc[o4 * 4 + 3]);
            }
        }
    } else {
        const unsigned short* Xb = (const unsigned short*)Xin;
        for (int ci = 0; ci < 32; ++ci) {
            float x = bf2f(Xb[(size_t)ci * NVOX + v]);
            const float4* wr = (const float4*)(ws + ci * 64);
#pragma unroll
            for (int o4 = 0; o4 < 16; ++o4) {
                float4 w4 = wr[o4];
                acc[o4 * 4 + 0] = fmaf(w4.x, x, acc[o4 * 4 + 0]);
                acc[o4 * 4 + 1] = fmaf(w4.y, x, acc[o4 * 4 + 1]);
                acc[o4 * 4 + 2] = fmaf(w4.z, x, acc[o4 * 4 + 2]);
                acc[o4 * 4 + 3] = fmaf(w4.w, x, acc[o4 * 4 + 3]);
            }
        }
    }
    float s = 0.f;
#pragma unroll
    for (int o = 0; o < 64; ++o) s = fmaf(acc[o], acc[o], s);
    float scale = 1.f / fmaxf(sqrtf(s), 1e-12f);

    unsigned int pk[32];
#pragma unroll
    for (int o = 0; o < 32; ++o)
        pk[o] = (unsigned int)f2bf(acc[2 * o] * scale) |
                ((unsigned int)f2bf(acc[2 * o + 1] * scale) << 16);
    uint4* outp = (uint4*)(Outp + v * 64);
#pragma unroll
    for (int j = 0; j < 8; ++j)
        outp[j] = make_uint4(pk[4 * j], pk[4 * j + 1], pk[4 * j + 2], pk[4 * j + 3]);
}

// ---------------------------------------------------------------------------
// Correlation via MFMA, v3: block = TWO y-rows (128 vox). The (dz,dy)
// windows of rows y,y+1 overlap in 4/5 slices -> iterate 30 staged slices
// (5 dz x 6 yc) instead of 2x25: staging bytes & barriers x0.6/voxel, and
// each slice's B-fragments (4 ds_read_b128) feed BOTH rows' MFMAs (LDS
// reads/voxel halved). Row r active when its dy=j-2-r is in [-2,2].
// A fragments loop-invariant in registers (4 per row). Deferred softmax
// tail per row, same arithmetic/k-order as before.
// ---------------------------------------------------------------------------
__global__ __launch_bounds__(256) void corr_kernel(
        const unsigned short* __restrict__ SP, const unsigned short* __restrict__ TP,
        unsigned short* __restrict__ X1, float* __restrict__ Out) {
    __shared__ __align__(16) unsigned short tpb[2][80 * 64];     // 20480 B
    __shared__ __align__(16) unsigned short sband[2][64 * 128];  // 32768 B

    const int t = threadIdx.x;
    const int wv = t >> 6, lane = t & 63;
    const int q = lane >> 4, l16 = lane & 15;
    const int x0 = wv * 16;

    // XCD-aware bijective swizzle (2048 = 8*256)
    const int bid = blockIdx.x;
    const int wg = (bid & 7) * 256 + (bid >> 3);
    const int z = wg >> 5, y = (wg & 31) * 2;
    const size_t vb0 = ((size_t)z * 64 + y) * 64;
    const size_t vb1 = vb0 + 64;

    // A fragments for both rows, once from global (loop-invariant)
    const unsigned short* ar0 = SP + (vb0 + x0 + l16) * 64 + q * 8;
    const unsigned short* ar1 = SP + (vb1 + x0 + l16) * 64 + q * 8;
    const bf16x8 a00 = *(const bf16x8*)(ar0);
    const bf16x8 a01 = *(const bf16x8*)(ar0 + 32);
    const bf16x8 a10 = *(const bf16x8*)(ar1);
    const bf16x8 a11 = *(const bf16x8*)(ar1 + 32);

    // DMA staging of slice (dz, j): 640 chunks (80 pos x 8), pre-swizzled src.
    auto stage_tp = [&](int it, int b) {
        const int zc = min(max(z + it / 6 - 2, 0), 63);
        const int yc = min(max(y - 2 + it % 6, 0), 63);
        const unsigned short* tb = TP + ((size_t)zc * 64 + yc) * 4096;
#pragma unroll
        for (int j = 0; j < 2; ++j) {
            int c = t + j * 256;
            int pp = c >> 3, cc = c & 7;
            int xc = min(max(pp - 2, 0), 63);
            gld16(tb + xc * 64 + ((cc ^ (pp & 7)) * 8),
                  &tpb[b][(wv * 64 + j * 256) * 8]);
        }
        if (wv < 2) {
            int c = 512 + wv * 64 + lane;
            int pp = c >> 3, cc = c & 7;
            int xc = min(max(pp - 2, 0), 63);
            gld16(tb + xc * 64 + ((cc ^ (pp & 7)) * 8),
                  &tpb[b][(512 + wv * 64) * 8]);
        }
    };

    stage_tp(0, 0);
    __syncthreads();

    int p = 0;
    for (int it = 0; it < 30; ++it) {
        if (it < 29) stage_tp(it + 1, p ^ 1);   // DMA overlaps compute below
        const int dz = it / 6, j = it % 6;
        const bool r0 = (j < 5), r1 = (j > 0);

        f32x4 acc0[2] = {{0.f, 0.f, 0.f, 0.f}, {0.f, 0.f, 0.f, 0.f}};
        f32x4 acc1[2] = {{0.f, 0.f, 0.f, 0.f}, {0.f, 0.f, 0.f, 0.f}};
        {
            const char* tb = (const char*)tpb[p];
#pragma unroll
            for (int nt = 0; nt < 2; ++nt) {
                const int pr = x0 + nt * 16 + l16;
                bf16x8 b0 = *(const bf16x8*)(tb + pr * 128 + ((q ^ (pr & 7)) * 16));
                bf16x8 b1 = *(const bf16x8*)(tb + pr * 128 + (((4 + q) ^ (pr & 7)) * 16));
                if (r0) {
                    acc0[nt] = __builtin_amdgcn_mfma_f32_16x16x32_bf16(a00, b0, acc0[nt], 0, 0, 0);
                    acc0[nt] = __builtin_amdgcn_mfma_f32_16x16x32_bf16(a01, b1, acc0[nt], 0, 0, 0);
                }
                if (r1) {
                    acc1[nt] = __builtin_amdgcn_mfma_f32_16x16x32_bf16(a10, b0, acc1[nt], 0, 0, 0);
                    acc1[nt] = __builtin_amdgcn_mfma_f32_16x16x32_bf16(a11, b1, acc1[nt], 0, 0, 0);
                }
            }
        }
        // band extraction per active row
        if (r0) {
            const int kb = dz * 25 + j * 5;
            char* sg = (char*)sband[0];
#pragma unroll
            for (int nt = 0; nt < 2; ++nt)
#pragma unroll
                for (int r = 0; r < 4; ++r) {
                    int ml = q * 4 + r;
                    int dxp = nt * 16 + l16 - ml;
                    if ((unsigned)dxp < 5u) {
                        int xl = x0 + ml;
                        *(unsigned short*)(sg + xl * 256 + (((kb + dxp) * 2) ^ ((xl & 7) << 4))) =
                            f2bf(acc0[nt][r]);
                    }
                }
        }
        if (r1) {
            const int kb = dz * 25 + (j - 1) * 5;
            char* sg = (char*)sband[1];
#pragma unroll
            for (int nt = 0; nt < 2; ++nt)
#pragma unroll
                for (int r = 0; r < 4; ++r) {
                    int ml = q * 4 + r;
                    int dxp = nt * 16 + l16 - ml;
                    if ((unsigned)dxp < 5u) {
                        int xl = x0 + ml;
                        *(unsigned short*)(sg + xl * 256 + (((kb + dxp) * 2) ^ ((xl & 7) << 4))) =
                            f2bf(acc1[nt][r]);
                    }
                }
        }
        __syncthreads();
        p ^= 1;
    }

    // ---- deferred softmax tail: 4 lanes per voxel, one pass per row ----
    for (int half = 0; half < 2; ++half) {
        const size_t vbase = half ? vb1 : vb0;
        const int vox = t >> 2, part = t & 3;
        const int sx = (vox & 7) << 4;
        const char* sg = (const char*)sband[half];
        uint4 u[4];
#pragma unroll
        for (int j = 0; j < 4; ++j)
            u[j] = *(const uint4*)(sg + vox * 256 + ((part * 64 + j * 16) ^ sx));

        float m = -1e30f, s2 = -1e30f;
#pragma unroll
        for (int j = 0; j < 4; ++j) {
            const unsigned int uu[4] = {u[j].x, u[j].y, u[j].z, u[j].w};
#pragma unroll
            for (int w = 0; w < 4; ++w) {
                int k = part * 32 + j * 8 + w * 2;
                float d0 = (k < 125) ? bflo(uu[w]) : -1e30f;
                float d1 = (k + 1 < 125) ? bfhi(uu[w]) : -1e30f;
                float lo0 = fminf(d0, m); m = fmaxf(d0, m); s2 = fmaxf(s2, lo0);
                float lo1 = fminf(d1, m); m = fmaxf(d1, m); s2 = fmaxf(s2, lo1);
            }
        }
#pragma unroll
        for (int off = 1; off <= 2; off <<= 1) {
            float om = __shfl_xor(m, off, 64);
            float os = __shfl_xor(s2, off, 64);
            float lo = fminf(m, om);
            m = fmaxf(m, om);
            s2 = fmaxf(fmaxf(s2, os), lo);
        }
        int kk = part * 32;
        int dz0 = kk / 25, rem = kk - dz0 * 25, dy0 = rem / 5, dx0 = rem - dy0 * 5;
        float fx = (float)(dx0 - 2), fy = (float)(dy0 - 2), fz = (float)(dz0 - 2);
        float Zs = 0.f, S1 = 0.f, Ox = 0.f, Oy = 0.f, Oz = 0.f;
#pragma unroll
        for (int j = 0; j < 4; ++j) {
            const unsigned int uu[4] = {u[j].x, u[j].y, u[j].z, u[j].w};
#pragma unroll
            for (int w = 0; w < 8; ++w) {
                int k = part * 32 + j * 8 + w;
                bool ok = (k < 125);
                float d = (w & 1) ? bfhi(uu[w >> 1]) : bflo(uu[w >> 1]);
                d = ok ? d : 0.f;                 // sanitize: garbage slot may be NaN
                float e = ok ? __expf(d - m) : 0.f;
                Zs += e; S1 = fmaf(e, d, S1);
                Ox = fmaf(e, fx, Ox); Oy = fmaf(e, fy, Oy); Oz = fmaf(e, fz, Oz);
                fx += 1.f;
                if (fx > 2.5f) { fx = -2.f; fy += 1.f; if (fy > 2.5f) { fy = -2.f; fz += 1.f; } }
            }
        }
#pragma unroll
        for (int off = 1; off <= 2; off <<= 1) {
            Zs += __shfl_xor(Zs, off, 64);
            S1 += __shfl_xor(S1, off, 64);
            Ox += __shfl_xor(Ox, off, 64);
            Oy += __shfl_xor(Oy, off, 64);
            Oz += __shfl_xor(Oz, off, 64);
        }
        if (part == 0) {
            float inv  = 1.f / fmaxf(Zs, 1e-8f);
            float eoz = Oz * inv, eoy = Oy * inv, eox = Ox * inv;
            float conf = fminf(inv, 1.f);
            float marg = fmaxf(conf - __expf(s2 - m) * inv, 0.f);
            float ent  = m + __logf(fmaxf(Zs, 1e-8f)) - S1 * inv;
            char* sgw = (char*)sband[half];
            *(unsigned short*)(sgw + vox * 256 + (250 ^ sx)) = f2bf(eoz);
            *(unsigned short*)(sgw + vox * 256 + (252 ^ sx)) = f2bf(eoy);
            *(unsigned short*)(sgw + vox * 256 + (254 ^ sx)) = f2bf(eox);
            const size_t v = vbase + vox;
            *(unsigned int*)(X1 + v * 160 + 128) =
                (unsigned int)f2bf(conf) | ((unsigned int)f2bf(ent) << 16);
            Out[v]                    = eoz;
            Out[(size_t)NVOX + v]     = eoy;
            Out[(size_t)2 * NVOX + v] = eox;
            Out[(size_t)3 * NVOX + v] = conf;
            Out[(size_t)4 * NVOX + v] = marg;
            Out[(size_t)5 * NVOX + v] = ent;
        }
    }
    __syncthreads();

    // X1 flush: ch 0..127 for both rows: 2 x 64 vox x 16 uint4
#pragma unroll
    for (int j = 0; j < 8; ++j) {
        int i = t + j * 256;                  // 0..2047
        int row = i >> 10, rr = i & 1023;
        int vox = rr >> 4, cc = rr & 15;
        *(uint4*)(X1 + ((row ? vb1 : vb0) + vox) * 160 + (size_t)cc * 8) =
            *(const uint4*)((const char*)sband[row] + vox * 256 + ((cc * 16) ^ ((vox & 7) << 4)));
    }
}

// ---------------------------------------------------------------------------
// 3x3x3 conv v3.1: as R6 (two y-rows, tap-major, 3-slot plane ring, DMA
// staging) + improved prefetch schedule: at dz-group entries (i=3,6) only
// plane s0+1 is staged with a drain barrier; s0+2 is prefetched during
// compute via the normal path (its ring slot is verifiably free: prior
// occupant's last read is >=1 barrier earlier, enumerated in the ledger).
// Halves the non-overlapped staging stall.
// ---------------------------------------------------------------------------
template <int XSTRIDE, int CPAD, int KC, int NLD, int MINW, bool TAIL>
__global__ __launch_bounds__(256, MINW) void conv3_kernel(
        const unsigned short* __restrict__ Xin, const unsigned short* __restrict__ Wf,
        const unsigned short* __restrict__ Wfe,
        const float* __restrict__ Bias, unsigned short* __restrict__ Out) {
    constexpr int SLOT = 66 * CPAD;
    constexpr int CH16 = CPAD / 8;
    __shared__ __align__(16) unsigned short lds[3 * SLOT];
    const int lin = blockIdx.x;
    const int wg = (lin & 7) * 256 + (lin >> 3);   // 2048 = 8*256, bijective
    const int z = wg >> 5;
    const int y = (wg & 31) * 2;
    const int t = threadIdx.x;
    const int wv = t >> 6, lane = t & 63;
    const int quad = lane >> 4, l16 = lane & 15;
    const int ml2 = (wv & 1) * 2;    // m-tile pair within each row
    const int nt2 = (wv >> 1) * 2;   // n-tile pair

    f32x4 acc[2][2][2] = {};         // [row][ml][nl]

    auto stage_plane = [&](int pidx) {
        const int zz = z + (pidx >> 2) - 1;
        const int py = y + (pidx & 3) - 1;
        if ((unsigned)zz >= 64u || (unsigned)py >= 64u) return;
        const unsigned short* base = Xin + (((size_t)zz * 64 + py) * 64) * XSTRIDE;
        unsigned short* dst = lds + (pidx % 3) * SLOT + CPAD;
#pragma unroll
        for (int i = 0; i < NLD; ++i) {
            int chunk = wv * 64 + lane + i * 256;    // 0 .. 64*CH16-1
            int xi = chunk / CH16;                   // global x (LDS row xi+1)
            int cc = chunk % CH16;
            gld16(base + xi * XSTRIDE + ((cc ^ ((xi + 1) & 7)) * 8),
                  dst + (size_t)(wv * 64 + i * 256) * 8);
        }
    };

    if (TAIL) {
        // im2col gather of ch 128/129 neighborhoods for BOTH rows into lds
        // scratch: ebuf[vox<128][kappa], kappa = tap*2 + ch, stride 72 shorts.
        unsigned short* ebuf = lds;
#pragma unroll
        for (int i2 = 0; i2 < 16; ++i2) {
            int i = t + i2 * 256;                 // 0..4095
            int vox = i >> 5, slot = i & 31;
            unsigned int val = 0u;
            int kap;
            if (slot < 27) {
                int ddz = slot / 9 - 1, ddy = (slot / 3) % 3 - 1, dxx = slot % 3 - 1;
                int zz = z + ddz, yy = y + (vox >> 6) + ddy, xx = (vox & 63) + dxx;
                kap = slot * 2;
                if ((unsigned)zz < 64u && (unsigned)yy < 64u && (unsigned)xx < 64u)
                    val = *(const unsigned int*)(Xin + (((size_t)zz * 64 + yy) * 64 + xx) * XSTRIDE + 128);
            } else {
                kap = 54 + (slot - 27) * 2;       // zero-fill kappa 54..63
            }
            *(unsigned int*)(ebuf + (size_t)vox * 72 + kap) = val;
        }
        __syncthreads();
#pragma unroll
        for (int kc = 0; kc < 2; ++kc) {
            bf16x8 bte[2];
#pragma unroll
            for (int nl = 0; nl < 2; ++nl)
                bte[nl] = *(const bf16x8*)(Wfe + (size_t)(kc * 4 + nt2 + nl) * 512 + lane * 8);
#pragma unroll
            for (int r = 0; r < 2; ++r)
#pragma unroll
            for (int ml = 0; ml < 2; ++ml) {
                bf16x8 a = *(const bf16x8*)(ebuf + (size_t)(r * 64 + (ml2 + ml) * 16 + l16) * 72 + (kc * 4 + quad) * 8);
#pragma unroll
                for (int nl = 0; nl < 2; ++nl)
                    acc[r][ml][nl] = __builtin_amdgcn_mfma_f32_16x16x32_bf16(a, bte[nl], acc[r][ml][nl], 0, 0, 0);
            }
        }
        __syncthreads();   // ebuf reads drained before slot staging overwrites
    }

    // zero halo rows 0 and 65 of all 3 slots (x = -1/64: always outside)
    if (t < 6 * CH16) {
        int sl = t / (2 * CH16), r2 = (t / CH16) & 1, c = t % CH16;
        *(uint4*)(&lds[(size_t)sl * SLOT + (size_t)(r2 * 65) * CPAD + c * 8]) =
            make_uint4(0u, 0u, 0u, 0u);
    }
    stage_plane(0);
    stage_plane(1);
    __syncthreads();   // drains DMA + halo zeros

    for (int i = 0; i < 9; ++i) {
        const int s0 = (i / 3) * 4 + i % 3;
        if (i == 3 || i == 6) {
            stage_plane(s0 + 1);   // ring can't hold it earlier
            __syncthreads();
        }
        if (s0 + 2 < 12) stage_plane(s0 + 2);   // prefetch (slot free; ledger)

        const int zz = z + i / 3 - 1;
        const int dy = i % 3 - 1;
        const bool zok = (unsigned)zz < 64u;
        const bool rok0 = zok && (unsigned)(y + dy) < 64u;
        const bool rok1 = zok && (unsigned)(y + 1 + dy) < 64u;
        const unsigned short* sb0 = lds + (size_t)(s0 % 3) * SLOT;
        const unsigned short* sb1 = lds + (size_t)((s0 + 1) % 3) * SLOT;
        if (rok0 || rok1) {
#pragma unroll
            for (int dx = 0; dx < 3; ++dx) {
                const int tap = (i / 3) * 9 + (i % 3) * 3 + dx;
                const unsigned short* wt = Wf + ((size_t)tap * KC * 4) * 512 + lane * 8;
                bf16x8 bf[KC][2];
#pragma unroll
                for (int kc = 0; kc < KC; ++kc)
#pragma unroll
                    for (int nl = 0; nl < 2; ++nl)
                        bf[kc][nl] = *(const bf16x8*)(wt + (size_t)(kc * 4 + nt2 + nl) * 512);
#pragma unroll
                for (int kc = 0; kc < KC; ++kc) {
#pragma unroll
                    for (int ml = 0; ml < 2; ++ml) {
                        const int row = (ml2 + ml) * 16 + l16 + dx;
                        const int co = ((kc * 4 + quad) ^ (row & 7)) * 8;
                        if (rok0) {
                            bf16x8 a = *(const bf16x8*)(&sb0[(size_t)row * CPAD + co]);
#pragma unroll
                            for (int nl = 0; nl < 2; ++nl)
                                acc[0][ml][nl] = __builtin_amdgcn_mfma_f32_16x16x32_bf16(a, bf[kc][nl], acc[0][ml][nl], 0, 0, 0);
                        }
                        if (rok1) {
                            bf16x8 a = *(const bf16x8*)(&sb1[(size_t)row * CPAD + co]);
#pragma unroll
                            for (int nl = 0; nl < 2; ++nl)
                                acc[1][ml][nl] = __builtin_amdgcn_mfma_f32_16x16x32_bf16(a, bf[kc][nl], acc[1][ml][nl], 0, 0, 0);
                        }
                    }
                }
            }
        }
        __syncthreads();
    }

#pragma unroll
    for (int r = 0; r < 2; ++r) {
        const size_t vb = ((size_t)z * 64 + (y + r)) * 64;
#pragma unroll
        for (int ml = 0; ml < 2; ++ml) {
#pragma unroll
            for (int nl = 0; nl < 2; ++nl) {
                const int oc = (nt2 + nl) * 16 + l16;
                const float bv = Bias[oc];
#pragma unroll
                for (int rr = 0; rr < 4; ++rr)
                    Out[(vb + (ml2 + ml) * 16 + quad * 4 + rr) * 64 + oc] =
                        f2bf(acc[r][ml][nl][rr] + bv);
            }
        }
    }
}

// ---------------------------------------------------------------------------
// Per-channel sum / sumsq over all voxels (InstanceNorm stats).
// ---------------------------------------------------------------------------
__global__ __launch_bounds__(256) void stats_kernel(
        const unsigned short* __restrict__ H, float* __restrict__ stats) {
    const int t = threadIdx.x;
    const int c = t & 63, g = t >> 6;
    float s = 0.f, q = 0.f;
    for (int v = blockIdx.x * 4 + g; v < NVOX; v += gridDim.x * 4) {
        float x = bf2f(H[(size_t)v * 64 + c]);
        s += x; q = fmaf(x, x, q);
    }
    __shared__ float ls[256], lq[256];
    ls[t] = s; lq[t] = q;
    __syncthreads();
    if (t < 64) {
        s = ls[t] + ls[t + 64] + ls[t + 128] + ls[t + 192];
        q = lq[t] + lq[t + 64] + lq[t + 128] + lq[t + 192];
        atomicAdd(&stats[c], s);
        atomicAdd(&stats[64 + c], q);
    }
}

__global__ void finalize_kernel(const float* __restrict__ stats, float* __restrict__ musr) {
    int c = threadIdx.x;
    if (c < 64) {
        float mu  = stats[c] * (1.0f / 262144.0f);
        float var = stats[64 + c] * (1.0f / 262144.0f) - mu * mu;
        musr[c] = mu;
        musr[64 + c] = rsqrtf(var + 1e-5f);
    }
}

// ---------------------------------------------------------------------------
// Elementwise InstanceNorm + exact GELU, [v][64] -> [v][64] bf16
// ---------------------------------------------------------------------------
__global__ __launch_bounds__(256) void norm_gelu_kernel(
        const unsigned short* __restrict__ H, const float* __restrict__ musr,
        unsigned short* __restrict__ G) {
    const size_t base = ((size_t)blockIdx.x * 256 + threadIdx.x) * 8;
    uint4 u = *(const uint4*)(H + base);
    const int c0 = (int)(base & 63);
    const unsigned int uu[4] = {u.x, u.y, u.z, u.w};
    unsigned int w[4];
#pragma unroll
    for (int p = 0; p < 4; ++p) {
        int c = c0 + p * 2;
        float x0 = (bflo(uu[p]) - musr[c]) * musr[64 + c];
        float x1 = (bfhi(uu[p]) - musr[c + 1]) * musr[64 + c + 1];
        float g0 = 0.5f * x0 * (1.f + erff(x0 * 0.70710678118f));
        float g1 = 0.5f * x1 * (1.f + erff(x1 * 0.70710678118f));
        w[p] = (unsigned int)f2bf(g0) | ((unsigned int)f2bf(g1) << 16);
    }
    *(uint4*)(G + base) = make_uint4(w[0], w[1], w[2], w[3]);
}

// ---------------------------------------------------------------------------
// Final: InstanceNorm + exact GELU on h2, write fp32 channel planes [64][v].
// ---------------------------------------------------------------------------
__global__ __launch_bounds__(256) void out_final_kernel(
        const unsigned short* __restrict__ H2, const float* __restrict__ musr,
        float* __restrict__ OutEnc) {
    __shared__ float tile[64 * 260];
    const int t = threadIdx.x;
    const size_t v0 = (size_t)blockIdx.x * 256;
#pragma unroll
    for (int i = 0; i < 8; ++i) {
        int chunk = t + i * 256;                  // 0..2047
        uint4 u = *(const uint4*)(H2 + v0 * 64 + (size_t)chunk * 8);
        int vox = chunk >> 3;
        int c0 = (chunk & 7) * 8;
        const unsigned int uu[4] = {u.x, u.y, u.z, u.w};
#pragma unroll
        for (int p = 0; p < 4; ++p) {
            int c = c0 + p * 2;
            float x0 = (bflo(uu[p]) - musr[c]) * musr[64 + c];
            float x1 = (bfhi(uu[p]) - musr[c + 1]) * musr[64 + c + 1];
            tile[c * 260 + vox]       = 0.5f * x0 * (1.f + erff(x0 * 0.70710678118f));
            tile[(c + 1) * 260 + vox] = 0.5f * x1 * (1.f + erff(x1 * 0.70710678118f));
        }
    }
    __syncthreads();
    const int c = t >> 2, sub = t & 3;
#pragma unroll
    for (int iter = 0; iter < 16; ++iter) {
        int fq = iter * 4 + sub;                  // float4 index 0..63
        float4 val = *(const float4*)(&tile[c * 260 + fq * 4]);
        *(float4*)(OutEnc + (size_t)c * NVOX + v0 + fq * 4) = val;
    }
}

// ---------------------------------------------------------------------------
extern "C" void kernel_launch(void* const* d_in, const int* in_sizes, int n_in,
                              void* d_out, int out_size, void* d_ws, size_t ws_size,
                              hipStream_t stream) {
    const void* src  = d_in[0];
    const void* tgt  = d_in[1];
    const void* wsrc = d_in[2];
    const void* bsrc = d_in[3];
    const void* wtgt = d_in[4];
    const void* btgt = d_in[5];
    const void* w1   = d_in[6];
    const void* b1   = d_in[7];
    const void* w2   = d_in[8];
    const void* b2   = d_in[9];
    float* out = (float*)d_out;   // fp32 outputs, 70*262144 elements

    char* ws = (char*)d_ws;
    unsigned short* TPb = (unsigned short*)(ws);                  // 33,554,432 B
    unsigned short* SPb = (unsigned short*)(ws + 33554432);       // 33,554,432 B
    unsigned short* X1  = (unsigned short*)(ws + 67108864);       // 83,886,080 B
    unsigned short* Wf1 = (unsigned short*)(ws + 150994944);      // main+tail frags
    unsigned short* Wf2 = (unsigned short*)(ws + 151547904);      //    221,184 B
    int*   flag   = (int*)  (ws + 151769088);
    float* fbias  = (float*)(ws + 151769152);                     // 256 f32
    float* stats1 = (float*)(ws + 151770176);                     // 128 f32
    float* musr1  = (float*)(ws + 151770688);
    float* stats2 = (float*)(ws + 151771200);
    float* musr2  = (float*)(ws + 151771712);
    unsigned short* H1 = SPb;
    unsigned short* G1 = TPb;
    unsigned short* H2 = X1;
    unsigned short* Wf1e = Wf1 + 27 * 4 * 4 * 512;                // tail frags

    (void)hipMemsetAsync(stats1, 0, 2048, stream);
    sniff_kernel<<<1, 256, 0, stream>>>((const unsigned short*)src, flag);
    prep_kernel<<<1313, 256, 0, stream>>>(w1, w2, bsrc, btgt, b1, b2, flag, Wf1, Wf2, fbias);
    proj_kernel<<<dim3(1024, 2), 256, 0, stream>>>(src, tgt, wsrc, wtgt, fbias, flag, SPb, TPb);
    corr_kernel<<<2048, 256, 0, stream>>>(SPb, TPb, X1, out);
    conv3_kernel<160, 128, 4, 4, 3, true><<<2048, 256, 0, stream>>>(X1, Wf1, Wf1e, fbias + 128, H1);
    stats_kernel<<<256, 256, 0, stream>>>(H1, stats1);
    finalize_kernel<<<1, 64, 0, stream>>>(stats1, musr1);
    norm_gelu_kernel<<<8192, 256, 0, stream>>>(H1, musr1, G1);
    conv3_kernel<64, 64, 2, 2, 4, false><<<2048, 256, 0, stream>>>(G1, Wf2, nullptr, fbias + 192, H2);
    stats_kernel<<<256, 256, 0, stream>>>(H2, stats2);
    finalize_kernel<<<1, 64, 0, stream>>>(stats2, musr2);
    out_final_kernel<<<1024, 256, 0, stream>>>(H2, musr2, out + 6 * (size_t)NVOX);
}